// Round 6
// baseline (777.125 us; speedup 1.0000x reference)
//
#include <hip/hip_runtime.h>

#define BATCH 256
#define SEQ   128
#define EDIM  300
#define PDIM  200
#define BSTOK (BATCH * SEQ)

#define F_RELU  1
#define F_ACCUM 2

typedef unsigned short u16;
typedef __attribute__((ext_vector_type(8))) short bf16x8;
typedef __attribute__((ext_vector_type(4))) float f32x4;

__device__ __forceinline__ u16 f2bf(float x) {
    unsigned u = __float_as_uint(x);
    unsigned r = u + 0x7fffu + ((u >> 16) & 1u);
    return (u16)(r >> 16);
}
__device__ __forceinline__ float bf2f(u16 h) {
    return __uint_as_float(((unsigned)h) << 16);
}

// ---------------------------------------------------------------------------
// Swizzled [128][32]-u16 LDS tile: 64B rows, 16B chunks, chunk XOR (row>>1)&3.
// 8KB per tile. Applied on BOTH write and read.
// ---------------------------------------------------------------------------
__device__ __forceinline__ unsigned char* swz16(unsigned char* base, int row, int chunk) {
    return base + row * 64 + (((chunk ^ (row >> 1)) & 3) << 4);
}

// 8 fp32 -> hi(trunc)/lo(residual) bf16, one 16B chunk each.
__device__ __forceinline__ void split_store8(const float* va,
    unsigned char* bH, unsigned char* bL, int row, int chunk)
{
    unsigned hp[4], lp[4];
    #pragma unroll
    for (int i = 0; i < 4; i++) {
        const unsigned u0 = __float_as_uint(va[2 * i]);
        const unsigned u1 = __float_as_uint(va[2 * i + 1]);
        const unsigned h0 = u0 & 0xffff0000u;
        const unsigned h1 = u1 & 0xffff0000u;
        hp[i] = (u0 >> 16) | h1;
        const float r0 = va[2 * i]     - __uint_as_float(h0);
        const float r1 = va[2 * i + 1] - __uint_as_float(h1);
        lp[i] = (__float_as_uint(r0) >> 16) | (__float_as_uint(r1) & 0xffff0000u);
    }
    *(uint4*)swz16(bH, row, chunk) = make_uint4(hp[0], hp[1], hp[2], hp[3]);
    *(uint4*)swz16(bL, row, chunk) = make_uint4(lp[0], lp[1], lp[2], lp[3]);
}

// RNE-rounded hi-only store (1-MFMA paths).
__device__ __forceinline__ void hi_store8(const float* va,
    unsigned char* bH, int row, int chunk)
{
    unsigned hp[4];
    #pragma unroll
    for (int i = 0; i < 4; i++)
        hp[i] = (unsigned)f2bf(va[2 * i]) | ((unsigned)f2bf(va[2 * i + 1]) << 16);
    *(uint4*)swz16(bH, row, chunk) = make_uint4(hp[0], hp[1], hp[2], hp[3]);
}

__device__ __forceinline__ void gload8(float* va, const float* __restrict__ src,
                                       bool ok)
{
    if (ok) {
        const float4 v0 = *(const float4*)(src);
        const float4 v1 = *(const float4*)(src + 4);
        va[0] = v0.x; va[1] = v0.y; va[2] = v0.z; va[3] = v0.w;
        va[4] = v1.x; va[5] = v1.y; va[6] = v1.z; va[7] = v1.w;
    } else {
        #pragma unroll
        for (int i = 0; i < 8; i++) va[i] = 0.f;
    }
}

__device__ __forceinline__ void kmask8(float* va, int kbase, int Kvalid)
{
    #pragma unroll
    for (int i = 0; i < 8; i++)
        va[i] = (kbase + i < Kvalid) ? va[i] : 0.f;
}

// gathered l2norm-embedding, zero k >= 300.
__device__ __forceinline__ void gather8(float* va, const float* __restrict__ erow,
                                        float nrm, int kb)
{
    if (kb + 8 <= EDIM) {
        const float4 v0 = *(const float4*)(erow + kb);
        const float4 v1 = *(const float4*)(erow + kb + 4);
        va[0] = v0.x; va[1] = v0.y; va[2] = v0.z; va[3] = v0.w;
        va[4] = v1.x; va[5] = v1.y; va[6] = v1.z; va[7] = v1.w;
    } else {
        #pragma unroll
        for (int i = 0; i < 8; i++)
            va[i] = (kb + i < EDIM) ? erow[kb + i] : 0.f;
    }
    #pragma unroll
    for (int i = 0; i < 8; i++) va[i] *= nrm;
}

#define MFMA3(ai, aj) \
    acc[ai][aj] = __builtin_amdgcn_mfma_f32_16x16x32_bf16(fah[ai], fbh[aj], acc[ai][aj], 0, 0, 0); \
    acc[ai][aj] = __builtin_amdgcn_mfma_f32_16x16x32_bf16(fah[ai], fbl[aj], acc[ai][aj], 0, 0, 0); \
    acc[ai][aj] = __builtin_amdgcn_mfma_f32_16x16x32_bf16(fal[ai], fbh[aj], acc[ai][aj], 0, 0, 0);

#define MFMA1(ai, aj) \
    acc[ai][aj] = __builtin_amdgcn_mfma_f32_16x16x32_bf16(fah[ai], fbh[aj], acc[ai][aj], 0, 0, 0);

// ---------------------------------------------------------------------------
// 8-wave (512-thread) geometry: wave covers 64x32 of the 128x128 tile.
//   wr = (wave>>2)*64 row offset; wc = (wave&3)*32 col offset; acc[4][2].
// Staging: sr = tid>>2 (row 0..127), q = tid&3 (16B chunk), 8 elems/thread.
// ---------------------------------------------------------------------------

// Coalesced transposed store of the 128x128 tile via LDS (stride 129), 512 thr.
__device__ __forceinline__ void store_transposed(
    float* __restrict__ PT, const f32x4 (*acc)[2], float* TR,
    int bn, int Nvalid, int wr, int wc, int lr, int quad, int tid, bool relu)
{
    #pragma unroll
    for (int h = 0; h < 2; h++) {
        __syncthreads();
        if ((wc >> 6) == h) {
            #pragma unroll
            for (int j = 0; j < 2; j++) {
                const int col = (wc & 63) + j * 16 + lr;   // 0..63 within half
                #pragma unroll
                for (int i = 0; i < 4; i++)
                    #pragma unroll
                    for (int r = 0; r < 4; r++) {
                        float v = acc[i][j][r];
                        if (relu) v = fmaxf(v, 0.f);
                        TR[col * 129 + wr + i * 16 + quad * 4 + r] = v;
                    }
            }
        }
        __syncthreads();
        const int row = tid >> 3;                 // 0..63
        const int gp = bn + h * 64 + row;
        if (gp < Nvalid) {
            float* dst = PT + (long long)gp * 128;
            for (int c = (tid & 7); c < 32; c += 8) {
                const int base = row * 129 + c * 4;
                *(float4*)(dst + c * 4) =
                    make_float4(TR[base], TR[base + 1], TR[base + 2], TR[base + 3]);
            }
        }
    }
}

// ---------------------------------------------------------------------------
// Merged phase-A projection GEMM (grid (5,512), 512 thr, XCD-swizzled).
// launch_bounds(512,6): reg cap 85 (R5 measured 56 VGPR + 32 AGPR = 88 at
// bound 4 -> allocator shaves 3) -> 3 blocks/CU = 24 waves. LDS 3x33280 OK.
// ---------------------------------------------------------------------------
__global__ __launch_bounds__(512, 6) void gemm_proj(
    const int* __restrict__ x1, const int* __restrict__ x2,
    const float* __restrict__ emb, const float* __restrict__ norms,
    const u16* __restrict__ W1h, const u16* __restrict__ W1l,
    const u16* __restrict__ W2h, const u16* __restrict__ W2l,
    float* __restrict__ T, float* __restrict__ F0, float* __restrict__ F1)
{
    __shared__ __align__(16) unsigned char smem[33280];   // staging 32KB; TR 33024B

    const int tid = threadIdx.x;
    const int id  = blockIdx.y * 5 + blockIdx.x;
    const int xcd = id & 7;
    const int s   = id >> 3;
    const int mt  = xcd + 8 * (s / 5);
    const int bm  = mt * 128;
    const int bn  = (s % 5) * 128;
    const bool side2 = mt >= 256;
    const bool wb = bn < 256;          // block-uniform precision tier

    const u16* Bh = side2 ? W2h : W1h;
    const u16* Bl = side2 ? W2l : W1l;
    float* F = side2 ? F1 : F0;
    const int fm = side2 ? bm - 32768 : bm;
    const int* toks = (side2 ? x2 - 32768 : x1) + bm;

    const int wave = tid >> 6;
    const int lane = tid & 63;
    const int wr   = (wave >> 2) * 64;
    const int wc   = (wave & 3) * 32;
    const int lr   = lane & 15;
    const int quad = lane >> 4;
    const int sr   = tid >> 2;
    const int q    = tid & 3;
    const int scf  = q * 8;

    const int tok = toks[sr];
    const float nrm = norms[tok];
    const float* erow = emb + (long long)tok * EDIM;

    const int gn = bn + sr;
    const bool bok = gn < 556;
    const u16* Bhp = Bh + (long long)gn * 320 + scf;
    const u16* Blp = Bl + (long long)gn * 320 + scf;

    f32x4 acc[4][2];
    #pragma unroll
    for (int i = 0; i < 4; i++)
        #pragma unroll
        for (int j = 0; j < 2; j++)
            acc[i][j] = (f32x4)(0.0f);

    for (int t = 0; t < 10; ++t) {
        float av[8];
        gather8(av, erow, nrm, t * 32 + scf);
        const uint4 bh = bok ? *(const uint4*)(Bhp + t * 32) : make_uint4(0,0,0,0);
        if (wb) {
            const uint4 bl = bok ? *(const uint4*)(Blp + t * 32) : make_uint4(0,0,0,0);
            split_store8(av, smem, smem + 8192, sr, q);
            *(uint4*)swz16(smem + 16384, sr, q) = bh;
            *(uint4*)swz16(smem + 24576, sr, q) = bl;
        } else {
            hi_store8(av, smem, sr, q);
            *(uint4*)swz16(smem + 16384, sr, q) = bh;
        }
        __syncthreads();

        bf16x8 fah[4], fbh[2];
        #pragma unroll
        for (int i = 0; i < 4; i++)
            fah[i] = *(const bf16x8*)swz16(smem, wr + i * 16 + lr, quad);
        #pragma unroll
        for (int j = 0; j < 2; j++)
            fbh[j] = *(const bf16x8*)swz16(smem + 16384, wc + j * 16 + lr, quad);
        if (wb) {
            bf16x8 fal[4], fbl[2];
            #pragma unroll
            for (int i = 0; i < 4; i++)
                fal[i] = *(const bf16x8*)swz16(smem + 8192, wr + i * 16 + lr, quad);
            #pragma unroll
            for (int j = 0; j < 2; j++)
                fbl[j] = *(const bf16x8*)swz16(smem + 24576, wc + j * 16 + lr, quad);
            #pragma unroll
            for (int i = 0; i < 4; i++)
                #pragma unroll
                for (int j = 0; j < 2; j++) { MFMA3(i, j) }
        } else {
            #pragma unroll
            for (int i = 0; i < 4; i++)
                #pragma unroll
                for (int j = 0; j < 2; j++) { MFMA1(i, j) }
        }
        __syncthreads();
    }

    if (wb) {
        float* Tb = T + (long long)mt * (PDIM * SEQ);
        store_transposed(Tb, acc, (float*)smem, bn, PDIM, wr, wc, lr, quad, tid, false);
    } else {
        #pragma unroll
        for (int i = 0; i < 4; i++) {
            #pragma unroll
            for (int j = 0; j < 2; j++) {
                const int idx = bn + wc + j * 16 + lr - 256;
                if (idx >= EDIM) continue;
                #pragma unroll
                for (int r = 0; r < 4; r++) {
                    const int gm = fm + wr + i * 16 + quad * 4 + r;
                    F[(long long)gm * EDIM + idx] = fmaxf(acc[i][j][r], 0.f);
                }
            }
        }
    }
}

// ---------------------------------------------------------------------------
// Fused xp GEMM (3-MFMA): acc = e @ wp_a (10 steps) + probs @ G (4 steps).
// grid (2,1,512), 512 thr. Stays at (512,4): dual-phase loop carries more
// live pointers (~95 peak regs); forcing 85 would spill (R1 lesson).
// ---------------------------------------------------------------------------
__global__ __launch_bounds__(512, 4) void gemm_xp(
    const float* __restrict__ P, float* __restrict__ T,
    const int* __restrict__ x1, const int* __restrict__ x2,
    const float* __restrict__ emb, const float* __restrict__ norms,
    const u16* __restrict__ W1h, const u16* __restrict__ W1l,
    const u16* __restrict__ W2h, const u16* __restrict__ W2l,
    float* __restrict__ XCAT)
{
    __shared__ __align__(16) unsigned char smem[33280];

    const int tid = threadIdx.x;
    const int bz  = blockIdx.z;
    const int bn  = blockIdx.x * 128;

    const int wave = tid >> 6;
    const int lane = tid & 63;
    const int wr   = (wave >> 2) * 64;
    const int wc   = (wave & 3) * 32;
    const int lr   = lane & 15;
    const int quad = lane >> 4;
    const int sr   = tid >> 2;
    const int q    = tid & 3;
    const int scf  = q * 8;

    const int* toks = (bz < BATCH) ? x1 + bz * SEQ : x2 + (bz - BATCH) * SEQ;
    const u16* Wh = (bz < BATCH) ? W1h : W2h;
    const u16* Wl = (bz < BATCH) ? W1l : W2l;
    const int tok = toks[sr];
    const float nrm = norms[tok];
    const float* erow = emb + (long long)tok * EDIM;
    const float* Pb = P + (long long)bz * (SEQ * SEQ);
    float* Tb = T + (long long)bz * (PDIM * SEQ);

    const int gn = bn + sr;
    const bool bok = gn < PDIM;
    const u16* Whp = Wh + (long long)gn * 320 + scf;
    const u16* Wlp = Wl + (long long)gn * 320 + scf;
    const float* Pp = Pb + (long long)sr * 128 + scf;
    const float* Tp = Tb + (long long)gn * 128 + scf;

    f32x4 acc[4][2];
    #pragma unroll
    for (int i = 0; i < 4; i++)
        #pragma unroll
        for (int j = 0; j < 2; j++)
            acc[i][j] = (f32x4)(0.0f);

    for (int t = 0; t < 14; ++t) {
        if (t < 10) {
            float av[8];
            gather8(av, erow, nrm, t * 32 + scf);
            const uint4 bh = bok ? *(const uint4*)(Whp + t * 32) : make_uint4(0,0,0,0);
            const uint4 bl = bok ? *(const uint4*)(Wlp + t * 32) : make_uint4(0,0,0,0);
            split_store8(av, smem, smem + 8192, sr, q);
            *(uint4*)swz16(smem + 16384, sr, q) = bh;
            *(uint4*)swz16(smem + 24576, sr, q) = bl;
        } else {
            float av[8], bv[8];
            gload8(av, Pp + (t - 10) * 32, true);
            gload8(bv, Tp + (t - 10) * 32, bok);
            split_store8(av, smem,         smem + 8192,  sr, q);
            split_store8(bv, smem + 16384, smem + 24576, sr, q);
        }
        __syncthreads();

        bf16x8 fah[4], fal[4], fbh[2], fbl[2];
        #pragma unroll
        for (int i = 0; i < 4; i++) {
            fah[i] = *(const bf16x8*)swz16(smem,        wr + i * 16 + lr, quad);
            fal[i] = *(const bf16x8*)swz16(smem + 8192, wr + i * 16 + lr, quad);
        }
        #pragma unroll
        for (int j = 0; j < 2; j++) {
            fbh[j] = *(const bf16x8*)swz16(smem + 16384, wc + j * 16 + lr, quad);
            fbl[j] = *(const bf16x8*)swz16(smem + 24576, wc + j * 16 + lr, quad);
        }
        #pragma unroll
        for (int i = 0; i < 4; i++)
            #pragma unroll
            for (int j = 0; j < 2; j++) { MFMA3(i, j) }
        __syncthreads();
    }

    const long long rowbase = (long long)bz * SEQ;
    #pragma unroll
    for (int i = 0; i < 4; i++) {
        #pragma unroll
        for (int j = 0; j < 2; j++) {
            const int gnn = bn + wc + j * 16 + lr;
            if (gnn >= PDIM) continue;
            #pragma unroll
            for (int r = 0; r < 4; r++) {
                const int gm = wr + i * 16 + quad * 4 + r;
                XCAT[(rowbase + gm) * 400 + gnn] = fmaxf(acc[i][j][r], 0.f);
            }
        }
    }
    store_transposed(Tb, acc, (float*)smem, bn, PDIM, wr, wc, lr, quad, tid, true);
}

// ---------------------------------------------------------------------------
// Flat split-bf16 MFMA GEMM. NM = 3 (split) or 1 (plain bf16 RNE). 512 thr.
// (512,6): 3 blocks/CU (reg-light, same structure as proj minus gather).
// ---------------------------------------------------------------------------
template <int NM>
__global__ __launch_bounds__(512, 6) void gemm_flat(
    const float* __restrict__ A,
    const u16* __restrict__ Bh, const u16* __restrict__ Bl,
    const u16* __restrict__ Bh2, const u16* __restrict__ Bl2, int Msplit,
    float* __restrict__ C, float* __restrict__ PO, const int* __restrict__ sizes,
    int M, int N, int Kp, int lda, int ldb, int ldc, int flags)
{
    constexpr int BOFF = (NM == 3) ? 16384 : 8192;
    __shared__ __align__(16) unsigned char smem[(NM == 3) ? 32768 : 16384];

    const int tid = threadIdx.x;
    int bx = blockIdx.x, by = blockIdx.y;
    if ((gridDim.y & 7) == 0) {
        const int gx = gridDim.x;
        const int id = by * gx + bx;
        const int xcd = id & 7;
        const int s = id >> 3;
        by = xcd + 8 * (s / gx);
        bx = s % gx;
    }
    const int bm = by * 128;
    const int bn = bx * 128;

    const int wave = tid >> 6;
    const int lane = tid & 63;
    const int wr   = (wave >> 2) * 64;
    const int wc   = (wave & 3) * 32;
    const int lr   = lane & 15;
    const int quad = lane >> 4;
    const int sr   = tid >> 2;
    const int q    = tid & 3;
    const int scf  = q * 8;

    if (bm >= Msplit) { Bh = Bh2; Bl = Bl2; }

    const float* Ap = A + (long long)(bm + sr) * lda + scf;
    const int gn = bn + sr;
    const bool bok = gn < N;
    const u16* Bhp = Bh + (long long)gn * ldb + scf;
    const u16* Blp = Bl + (long long)gn * ldb + scf;

    f32x4 acc[4][2];
    #pragma unroll
    for (int i = 0; i < 4; i++)
        #pragma unroll
        for (int j = 0; j < 2; j++)
            acc[i][j] = (f32x4)(0.0f);

    const int NT = Kp >> 5;
    for (int t = 0; t < NT; ++t) {
        float av[8];
        gload8(av, Ap + t * 32, true);
        const uint4 bh = bok ? *(const uint4*)(Bhp + t * 32) : make_uint4(0,0,0,0);
        if constexpr (NM == 3) {
            const uint4 bl = bok ? *(const uint4*)(Blp + t * 32) : make_uint4(0,0,0,0);
            split_store8(av, smem, smem + 8192, sr, q);
            *(uint4*)swz16(smem + BOFF,        sr, q) = bh;
            *(uint4*)swz16(smem + BOFF + 8192, sr, q) = bl;
        } else {
            hi_store8(av, smem, sr, q);
            *(uint4*)swz16(smem + BOFF, sr, q) = bh;
        }
        __syncthreads();

        bf16x8 fah[4], fbh[2];
        #pragma unroll
        for (int i = 0; i < 4; i++)
            fah[i] = *(const bf16x8*)swz16(smem, wr + i * 16 + lr, quad);
        #pragma unroll
        for (int j = 0; j < 2; j++)
            fbh[j] = *(const bf16x8*)swz16(smem + BOFF, wc + j * 16 + lr, quad);
        if constexpr (NM == 3) {
            bf16x8 fal[4], fbl[2];
            #pragma unroll
            for (int i = 0; i < 4; i++)
                fal[i] = *(const bf16x8*)swz16(smem + 8192, wr + i * 16 + lr, quad);
            #pragma unroll
            for (int j = 0; j < 2; j++)
                fbl[j] = *(const bf16x8*)swz16(smem + BOFF + 8192, wc + j * 16 + lr, quad);
            #pragma unroll
            for (int i = 0; i < 4; i++)
                #pragma unroll
                for (int j = 0; j < 2; j++) { MFMA3(i, j) }
        } else {
            #pragma unroll
            for (int i = 0; i < 4; i++)
                #pragma unroll
                for (int j = 0; j < 2; j++) { MFMA1(i, j) }
        }
        __syncthreads();
    }

    const int sz = PO ? sizes[bm >> 7] : 0;
    float ps[2] = {0.f, 0.f};
    #pragma unroll
    for (int j = 0; j < 2; j++) {
        const int gnn = bn + wc + j * 16 + lr;
        const bool gok = gnn < N;
        #pragma unroll
        for (int i = 0; i < 4; i++) {
            #pragma unroll
            for (int r = 0; r < 4; r++) {
                const int row = wr + i * 16 + quad * 4 + r;
                const int gm = bm + row;
                float v = acc[i][j][r];
                if (flags & F_RELU) v = fmaxf(v, 0.f);
                if (gok && C) C[(long long)gm * ldc + gnn] = v;
                if (PO && row < sz) ps[j] += v;
            }
        }
    }
    if (PO) {
        #pragma unroll
        for (int j = 0; j < 2; j++) {
            ps[j] += __shfl_xor(ps[j], 16);
            ps[j] += __shfl_xor(ps[j], 32);
        }
        float* PS = (float*)smem;
        __syncthreads();
        if (wr == 0 && quad == 0) {
            #pragma unroll
            for (int j = 0; j < 2; j++) PS[wc + j * 16 + lr] = ps[j];
        }
        __syncthreads();
        if (wr == 64 && quad == 0) {
            #pragma unroll
            for (int j = 0; j < 2; j++) PS[wc + j * 16 + lr] += ps[j];
        }
        __syncthreads();
        if (tid < 128) {
            const int gnn = bn + tid;
            if (gnn < N) PO[(long long)(bm >> 7) * N + gnn] = PS[tid];
        }
    }
}

// ---------------------------------------------------------------------------
// Batched MFMA GEMM, NT layout, 512 thr.
// MODE 0 (3-MFMA split, (512,6)); MODE 1 (att: dist-bias + row softmax);
// MODE 2 (sim: mask + row softmax -> C + col softmax^T -> PT).
// Softmax scratch stride 132 floats; 4-lane-group scans (32 cols/thread).
// ---------------------------------------------------------------------------
#define SLD 132
template <int MODE>
__global__ __launch_bounds__(512, (MODE == 0) ? 6 : 2) void gemm_bat(
    const float* __restrict__ A, const float* __restrict__ Aalt,
    const float* __restrict__ B, const float* __restrict__ Balt,
    float* __restrict__ C, float* __restrict__ PT,
    int N, int Kvalid, int Kp, int lda, int ldb, int ldc,
    long long sA, long long sB, long long sC, long long sPT,
    int flags, const float* __restrict__ bias_ptr, const int* __restrict__ sizes,
    int same_ab)
{
    constexpr int NM = (MODE == 0) ? 3 : 1;
    constexpr int BOFF = (NM == 3) ? 16384 : 8192;
    constexpr int SMB  = (MODE == 0) ? 32768 : (128 * SLD * 4);  // 67584
    __shared__ __align__(16) unsigned char smem[SMB];

    const int bz = blockIdx.z;
    long long zb = bz;
    const float* Ause = A;
    const float* Buse = B;
    if (Aalt && bz >= BATCH) { Ause = Aalt; Buse = Balt; zb = bz - BATCH; }
    Ause += zb * sA;
    Buse += zb * sB;
    C += (long long)bz * sC;
    if (PT) PT += (long long)bz * sPT;

    const int tid  = threadIdx.x;
    const int bn   = blockIdx.x * 128;
    const int wave = tid >> 6;
    const int lane = tid & 63;
    const int wr   = (wave >> 2) * 64;
    const int wc   = (wave & 3) * 32;
    const int lr   = lane & 15;
    const int quad = lane >> 4;
    const int sr   = tid >> 2;
    const int q    = tid & 3;
    const int scf  = q * 8;

    f32x4 acc[4][2];
    #pragma unroll
    for (int i = 0; i < 4; i++)
        #pragma unroll
        for (int j = 0; j < 2; j++)
            acc[i][j] = (f32x4)(0.0f);

    const float* Apt = Ause + (long long)sr * lda + scf;
    const int gn = bn + sr;
    const bool bok = gn < N;
    const float* Bpt = Buse + (long long)gn * ldb + scf;

    const int NT = Kp >> 5;
    for (int t = 0; t < NT; ++t) {
        float av[8];
        gload8(av, Apt + t * 32, true);
        kmask8(av, t * 32 + scf, Kvalid);
        if constexpr (NM == 3) split_store8(av, smem, smem + 8192, sr, q);
        else                   hi_store8(av, smem, sr, q);
        if (!same_ab) {
            float bv[8];
            gload8(bv, Bpt + t * 32, bok);
            kmask8(bv, t * 32 + scf, Kvalid);
            if constexpr (NM == 3) split_store8(bv, smem + BOFF, smem + BOFF + 8192, sr, q);
            else                   hi_store8(bv, smem + BOFF, sr, q);
        }
        __syncthreads();

        unsigned char* rbB = same_ab ? smem : smem + BOFF;
        bf16x8 fah[4], fbh[2];
        #pragma unroll
        for (int i = 0; i < 4; i++)
            fah[i] = *(const bf16x8*)swz16(smem, wr + i * 16 + lr, quad);
        #pragma unroll
        for (int j = 0; j < 2; j++)
            fbh[j] = *(const bf16x8*)swz16(rbB, wc + j * 16 + lr, quad);
        if constexpr (NM == 3) {
            bf16x8 fal[4], fbl[2];
            #pragma unroll
            for (int i = 0; i < 4; i++)
                fal[i] = *(const bf16x8*)swz16(smem + 8192, wr + i * 16 + lr, quad);
            #pragma unroll
            for (int j = 0; j < 2; j++)
                fbl[j] = *(const bf16x8*)swz16(rbB + 8192, wc + j * 16 + lr, quad);
            #pragma unroll
            for (int i = 0; i < 4; i++)
                #pragma unroll
                for (int j = 0; j < 2; j++) { MFMA3(i, j) }
        } else {
            #pragma unroll
            for (int i = 0; i < 4; i++)
                #pragma unroll
                for (int j = 0; j < 2; j++) { MFMA1(i, j) }
        }
        __syncthreads();
    }

    if (MODE == 1) {
        float* S = (float*)smem;
        const float bias = bias_ptr[0];
        #pragma unroll
        for (int i = 0; i < 4; i++) {
            #pragma unroll
            for (int j = 0; j < 2; j++) {
                const int col = wc + j * 16 + lr;
                #pragma unroll
                for (int r = 0; r < 4; r++) {
                    const int row = wr + i * 16 + quad * 4 + r;
                    int d = row - col; d = d < 0 ? -d : d;
                    S[row * SLD + col] = acc[i][j][r] + ((d >= 10) ? bias : 0.f);
                }
            }
        }
        __syncthreads();
        const int row = tid >> 2;
        const int qd  = (tid & 3) * 32;
        float* Sr = S + row * SLD + qd;
        float mx = -1e30f;
        #pragma unroll
        for (int c = 0; c < 8; c++) {
            const float4 v = *(const float4*)(Sr + c * 4);
            mx = fmaxf(fmaxf(fmaxf(mx, v.x), fmaxf(v.y, v.z)), v.w);
        }
        mx = fmaxf(mx, __shfl_xor(mx, 1));
        mx = fmaxf(mx, __shfl_xor(mx, 2));
        float sum = 0.f;
        #pragma unroll
        for (int c = 0; c < 8; c++) {
            float4 v = *(const float4*)(Sr + c * 4);
            v.x = __expf(v.x - mx); v.y = __expf(v.y - mx);
            v.z = __expf(v.z - mx); v.w = __expf(v.w - mx);
            sum += (v.x + v.y) + (v.z + v.w);
            *(float4*)(Sr + c * 4) = v;
        }
        sum += __shfl_xor(sum, 1);
        sum += __shfl_xor(sum, 2);
        const float inv = 1.f / sum;
        #pragma unroll
        for (int c = 0; c < 8; c++) {
            float4 v = *(const float4*)(Sr + c * 4);
            v.x *= inv; v.y *= inv; v.z *= inv; v.w *= inv;
            *(float4*)&C[(long long)row * ldc + qd + c * 4] = v;
        }
    } else if (MODE == 2) {
        float* S = (float*)smem;
        const int s1 = sizes[bz];
        const int s2 = sizes[BATCH + bz];
        #pragma unroll
        for (int i = 0; i < 4; i++) {
            #pragma unroll
            for (int j = 0; j < 2; j++) {
                const int col = wc + j * 16 + lr;
                #pragma unroll
                for (int r = 0; r < 4; r++) {
                    const int row = wr + i * 16 + quad * 4 + r;
                    float v = acc[i][j][r];
                    if (row >= s1 || col >= s2) v = 0.f;
                    S[row * SLD + col] = v;
                }
            }
        }
        __syncthreads();
        const int row = tid >> 2;
        const int qd  = (tid & 3) * 32;
        {
            // row softmax (no writeback: column pass needs original S)
            const float* Sr = S + row * SLD + qd;
            float mx = -1e30f;
            #pragma unroll
            for (int c = 0; c < 8; c++) {
                const float4 v = *(const float4*)(Sr + c * 4);
                mx = fmaxf(fmaxf(fmaxf(mx, v.x), fmaxf(v.y, v.z)), v.w);
            }
            mx = fmaxf(mx, __shfl_xor(mx, 1));
            mx = fmaxf(mx, __shfl_xor(mx, 2));
            float sum = 0.f;
            #pragma unroll
            for (int c = 0; c < 8; c++) {
                const float4 v = *(const float4*)(Sr + c * 4);
                sum += (__expf(v.x - mx) + __expf(v.y - mx))
                     + (__expf(v.z - mx) + __expf(v.w - mx));
            }
            sum += __shfl_xor(sum, 1);
            sum += __shfl_xor(sum, 2);
            const float inv = 1.f / sum;
            #pragma unroll
            for (int c = 0; c < 8; c++) {
                const float4 v = *(const float4*)(Sr + c * 4);
                float4 o;
                o.x = __expf(v.x - mx) * inv; o.y = __expf(v.y - mx) * inv;
                o.z = __expf(v.z - mx) * inv; o.w = __expf(v.w - mx) * inv;
                *(float4*)&C[(long long)row * 128 + qd + c * 4] = o;
            }
        }
        {
            // column softmax -> PT (column = tid>>2, rows qd..qd+31)
            const int colx = row;
            float mx = -1e30f;
            for (int r = 0; r < 32; r++)
                mx = fmaxf(mx, S[(qd + r) * SLD + colx]);
            mx = fmaxf(mx, __shfl_xor(mx, 1));
            mx = fmaxf(mx, __shfl_xor(mx, 2));
            float sum = 0.f;
            for (int r = 0; r < 32; r++)
                sum += __expf(S[(qd + r) * SLD + colx] - mx);
            sum += __shfl_xor(sum, 1);
            sum += __shfl_xor(sum, 2);
            const float inv = 1.f / sum;
            #pragma unroll
            for (int r4 = 0; r4 < 8; r4++) {
                float4 o;
                o.x = __expf(S[(qd + r4 * 4 + 0) * SLD + colx] - mx) * inv;
                o.y = __expf(S[(qd + r4 * 4 + 1) * SLD + colx] - mx) * inv;
                o.z = __expf(S[(qd + r4 * 4 + 2) * SLD + colx] - mx) * inv;
                o.w = __expf(S[(qd + r4 * 4 + 3) * SLD + colx] - mx) * inv;
                *(float4*)&PT[(long long)colx * 128 + qd + r4 * 4] = o;
            }
        }
    } else {
        const int s1 = sizes ? sizes[bz] : SEQ;
        const int s2 = sizes ? sizes[BATCH + bz] : SEQ;
        #pragma unroll
        for (int i = 0; i < 4; i++) {
            #pragma unroll
            for (int j = 0; j < 2; j++) {
                const int gnn = bn + wc + j * 16 + lr;
                if (gnn >= N) continue;
                #pragma unroll
                for (int r = 0; r < 4; r++) {
                    const int gm = wr + i * 16 + quad * 4 + r;
                    float v = acc[i][j][r];
                    if (sizes && (gm >= s1 || gnn >= s2)) v = 0.f;
                    if (flags & F_ACCUM) v += C[(long long)gm * ldc + gnn];
                    if (flags & F_RELU)  v = fmaxf(v, 0.f);
                    C[(long long)gm * ldc + gnn] = v;
                    if (PT) PT[(long long)gnn * 128 + gm] = v;
                }
            }
        }
    }
}

// All weight transposes + hi/lo splits in one launch.
struct WEnt { const float* src; u16* H; u16* L; int K, N, Kp, rowStart; };
struct WTab { WEnt e[11]; };
__global__ void convert_all(WTab t)
{
    const int row = blockIdx.y;
    const int k = blockIdx.x * 256 + threadIdx.x;
    #pragma unroll
    for (int s = 0; s < 11; s++) {
        const WEnt w = t.e[s];
        if (row >= w.rowStart && row < w.rowStart + w.N) {
            const int n = row - w.rowStart;
            if (k < w.Kp) {
                const float v = (k < w.K) ? w.src[(long long)k * w.N + n] : 0.f;
                const u16 h = f2bf(v);
                w.H[(long long)n * w.Kp + k] = h;
                w.L[(long long)n * w.Kp + k] = f2bf(v - bf2f(h));
            }
            return;
        }
    }
}

__global__ void norms_kernel(const float* __restrict__ emb, float* __restrict__ norms)
{
    const int r = blockIdx.x;
    const int lane = threadIdx.x;
    const float* row = emb + (long long)r * EDIM;
    float ss = 0.f;
    #pragma unroll
    for (int i = 0; i < 5; i++) {
        const int c = lane + i * 64;
        const float f = (c < EDIM) ? row[c] : 0.f;
        ss += f * f;
    }
    #pragma unroll
    for (int o = 32; o > 0; o >>= 1) ss += __shfl_xor(ss, o);
    if (lane == 0) norms[r] = rsqrtf(fmaxf(ss, 1e-12f));
}

__global__ void sizes_kernel(const int* __restrict__ x1, const int* __restrict__ x2,
                             int* __restrict__ sizes)
{
    const int b = blockIdx.x;
    const int side = blockIdx.y;
    const int* x = (side ? x2 : x1) + b * SEQ;
    const int nz = (x[threadIdx.x] != 0) ? 1 : 0;
    const unsigned long long bal = __ballot(nz);
    __shared__ int part[2];
    if ((threadIdx.x & 63) == 0) part[threadIdx.x >> 6] = __popcll(bal);
    __syncthreads();
    if (threadIdx.x == 0) sizes[side * BATCH + b] = part[0] + part[1];
}

__global__ void agg_kernel(const float* __restrict__ v1s, const float* __restrict__ v2s,
                           const float* __restrict__ w_agg, float* __restrict__ y)
{
    const int b = blockIdx.x;
    const int lane = threadIdx.x;
    float a0 = 0.f, a1 = 0.f, a2 = 0.f;
    for (int k = lane; k < 800; k += 64) {
        const float v = (k < 400) ? v1s[b * 400 + k] : v2s[b * 400 + k - 400];
        a0 = fmaf(v, w_agg[k * 3 + 0], a0);
        a1 = fmaf(v, w_agg[k * 3 + 1], a1);
        a2 = fmaf(v, w_agg[k * 3 + 2], a2);
    }
    #pragma unroll
    for (int o = 32; o > 0; o >>= 1) {
        a0 += __shfl_xor(a0, o);
        a1 += __shfl_xor(a1, o);
        a2 += __shfl_xor(a2, o);
    }
    if (lane == 0) {
        y[b * 3 + 0] = fmaxf(a0, 0.f);
        y[b * 3 + 1] = fmaxf(a1, 0.f);
        y[b * 3 + 2] = fmaxf(a2, 0.f);
    }
}

extern "C" void kernel_launch(void* const* d_in, const int* in_sizes, int n_in,
                              void* d_out, int out_size, void* d_ws, size_t ws_size,
                              hipStream_t stream)
{
    (void)in_sizes; (void)n_in; (void)out_size; (void)ws_size;
    const int*   x1         = (const int*)d_in[0];
    const int*   x2         = (const int*)d_in[1];
    const float* emb        = (const float*)d_in[2];
    const float* w_intra    = (const float*)d_in[3];
    const float* bias_intra = (const float*)d_in[4];
    const float* w_proj1    = (const float*)d_in[5];
    const float* w_proj2    = (const float*)d_in[6];
    const float* w_att      = (const float*)d_in[7];
    const float* w_cmp1     = (const float*)d_in[8];
    const float* w_cmp2     = (const float*)d_in[9];
    const float* w_agg      = (const float*)d_in[10];
    float* y  = (float*)d_out;
    float* ws = (float*)d_ws;

    // ---- workspace (floats); total ~58.64M fl = 234.6 MB ----
    float* X1CAT = ws;                        // [32768,400]: x1p | beta; phase A: F side-2
    float* X2CAT = X1CAT + 13107200;          // [32768,400]: x2p | alpha (contig)
    float* T     = X2CAT + 13107200;          // [512,200,128]: G^T -> x_proj^T
    float* FBUF  = T + 13107200;              // [32768,300] intra f side-1
    float* ATT   = FBUF + 9830400;            // [512,128,128] probs (dead after xp)
    float* POOL  = ATT + 8388608;             // [512,400] pooled v1|v2
    int*   SIZES = (int*)(POOL + 204800);     // [2,256] + pad
    float* NORMS = (float*)(SIZES + 512);     // [32000] + pad
    u16*   W1H   = (u16*)(NORMS + 32768);     // side-1 stack [556][320]: wp_b|z56|intra
    u16*   W1L   = W1H + 177920;
    u16*   W2H   = W1L + 177920;              // side-2 stack [556][320]
    u16*   W2L   = W2H + 177920;
    u16*   WAH   = W2L + 177920;              // w_att^T  [200][224]
    u16*   WAL   = WAH + 44800;
    u16*   WC1H  = WAL + 44800;               // w_cmp1^T [400][416]
    u16*   WC1L  = WC1H + 166400;
    u16*   WC2H  = WC1L + 166400;
    u16*   WC2L  = WC2H + 166400;
    u16*   WPA1H = WC2L + 166400;             // wp_a side1 [200][320]
    u16*   WPA1L = WPA1H + 64000;
    u16*   WPA2H = WPA1L + 64000;
    u16*   WPA2L = WPA2H + 64000;

    // phase-A alias: side-2 intra f lives in X1CAT region (dead until xp)
    float* F1X = X1CAT;                       // [32768,300]
    // phase-B aliases: F12 spans FBUF + head of ATT (probs dead by then)
    float* F12 = FBUF;                        // [65536,200] f1|f2
    float* F2  = FBUF + 6553600;
    // sim outputs alias the f slots they consumed (block-local WAR only):
    float* SIMP = F2;                         // probs slot bz at F2  + bz*25600
    float* SMTP = F12;                        // probs^T slot bz at F12 + bz*25600
    float* T1  = T;
    float* T2  = T + 6553600;

    const long long sbSS = (long long)SEQ * SEQ;     // 16384
    const long long sbF  = (long long)SEQ * EDIM;    // 38400
    const long long sbFP = 25600;                    // f1/f2 slot stride (128*200)
    const long long sbC  = (long long)SEQ * 400;     // 51200
    const long long sbT  = (long long)PDIM * SEQ;    // 25600

    sizes_kernel<<<dim3(BATCH, 2), 128, 0, stream>>>(x1, x2, SIZES);
    norms_kernel<<<32000, 64, 0, stream>>>(emb, NORMS);

    {
        WTab t;
        t.e[0]  = { w_proj1 + 300 * 200, W1H,             W1L,             300, 200, 320, 0    };
        t.e[1]  = { w_intra,             W1H + 200 * 320, W1L + 200 * 320,   0,  56, 320, 200  };
        t.e[2]  = { w_intra,             W1H + 256 * 320, W1L + 256 * 320, 300, 300, 320, 256  };
        t.e[3]  = { w_proj2 + 300 * 200, W2H,             W2L,             300, 200, 320, 556  };
        t.e[4]  = { w_intra,             W2H + 200 * 320, W2L + 200 * 320,   0,  56, 320, 756  };
        t.e[5]  = { w_intra,             W2H + 256 * 320, W2L + 256 * 320, 300, 300, 320, 812  };
        t.e[6]  = { w_att,               WAH,             WAL,             200, 200, 224, 1112 };
        t.e[7]  = { w_cmp1,              WC1H,            WC1L,            400, 400, 416, 1312 };
        t.e[8]  = { w_cmp2,              WC2H,            WC2L,            400, 400, 416, 1712 };
        t.e[9]  = { w_proj1,             WPA1H,           WPA1L,           300, 200, 320, 2112 };
        t.e[10] = { w_proj2,             WPA2H,           WPA2L,           300, 200, 320, 2312 };
        convert_all<<<dim3(2, 2512), 256, 0, stream>>>(t);
    }

    // -------- phase A --------
    // merged proj (both sides): T[0:512] = (e@wp_b)^T; f side1 -> FBUF, side2 -> F1X
    gemm_proj<<<dim3(5, 512), 512, 0, stream>>>(
        x1, x2, emb, NORMS, W1H, W1L, W2H, W2L, T, FBUF, F1X);
    // merged att (512 batches, 1-MFMA): probs = rowsoftmax(f f^T + dbias) -> ATT
    gemm_bat<1><<<dim3(1, 1, 2 * BATCH), 512, 0, stream>>>(
        FBUF, F1X, FBUF, nullptr, ATT, nullptr,
        SEQ, EDIM, 320, EDIM, EDIM, SEQ, sbF, sbF, sbSS, 0,
        0, bias_intra, nullptr, 1);
    // fused xp (3-MFMA): XCAT[:,0:200] = relu(e@wp_a + probs@G); x_proj^T -> T
    gemm_xp<<<dim3(2, 1, 2 * BATCH), 512, 0, stream>>>(
        ATT, T, x1, x2, emb, NORMS, WPA1H, WPA1L, WPA2H, WPA2L, X1CAT);

    // -------- phase B --------
    // f1|f2 = relu(x_proj @ w_att)  [1-MFMA; A cols 200:224 garbage*0]
    gemm_flat<1><<<dim3(2, 512), 512, 0, stream>>>(
        X1CAT, WAH, WAL, WAH, WAL, 1 << 30, F12, nullptr, nullptr,
        2 * BSTOK, PDIM, 224, 400, 224, PDIM, F_RELU);
    // fused sim (1-MFMA): mask(f1 f2^T) -> rowsm over f2 slot + colsm^T over f1 slot
    gemm_bat<2><<<dim3(1, 1, BATCH), 512, 0, stream>>>(
        F12, nullptr, F2, nullptr, SIMP, SMTP,
        SEQ, PDIM, 224, PDIM, PDIM, SEQ, sbFP, sbFP, sbFP, sbFP,
        0, nullptr, SIZES, 0);
    // beta (bz<256) / alpha (bz>=256) -> X1CAT/X2CAT cols 200:400  [3-MFMA]
    gemm_bat<0><<<dim3(2, 1, 2 * BATCH), 512, 0, stream>>>(
        SIMP, SMTP, T2, T1, X1CAT + 200, nullptr,
        PDIM, SEQ, SEQ, SEQ, SEQ, 400, sbFP, sbT, sbC, 0,
        0, nullptr, nullptr, 0);

    // -------- phase C: fused compare + masked pool, aggregate [3-MFMA] --------
    gemm_flat<3><<<dim3(4, 512), 512, 0, stream>>>(
        X1CAT, WC1H, WC1L, WC2H, WC2L, BSTOK,
        nullptr, POOL, SIZES,
        2 * BSTOK, 400, 416, 400, 416, 400, F_RELU);
    agg_kernel<<<BATCH, 64, 0, stream>>>(POOL, POOL + 102400, w_agg, y);
}

// Round 7
// 462.073 us; speedup vs baseline: 1.6818x; 1.6818x over previous
//
#include <hip/hip_runtime.h>

#define BATCH 256
#define SEQ   128
#define EDIM  300
#define PDIM  200
#define BSTOK (BATCH * SEQ)

#define F_RELU  1
#define F_ACCUM 2

typedef unsigned short u16;
typedef __attribute__((ext_vector_type(8))) short bf16x8;
typedef __attribute__((ext_vector_type(4))) float f32x4;

__device__ __forceinline__ u16 f2bf(float x) {
    unsigned u = __float_as_uint(x);
    unsigned r = u + 0x7fffu + ((u >> 16) & 1u);
    return (u16)(r >> 16);
}
__device__ __forceinline__ float bf2f(u16 h) {
    return __uint_as_float(((unsigned)h) << 16);
}

// ---------------------------------------------------------------------------
// Swizzled [128][32]-u16 LDS tile: 64B rows, 16B chunks, chunk XOR (row>>1)&3.
// 8KB per tile. Applied on BOTH write and read.
// ---------------------------------------------------------------------------
__device__ __forceinline__ unsigned char* swz16(unsigned char* base, int row, int chunk) {
    return base + row * 64 + (((chunk ^ (row >> 1)) & 3) << 4);
}

// 8 fp32 -> hi(trunc)/lo(residual) bf16, one 16B chunk each.
__device__ __forceinline__ void split_store8(const float* va,
    unsigned char* bH, unsigned char* bL, int row, int chunk)
{
    unsigned hp[4], lp[4];
    #pragma unroll
    for (int i = 0; i < 4; i++) {
        const unsigned u0 = __float_as_uint(va[2 * i]);
        const unsigned u1 = __float_as_uint(va[2 * i + 1]);
        const unsigned h0 = u0 & 0xffff0000u;
        const unsigned h1 = u1 & 0xffff0000u;
        hp[i] = (u0 >> 16) | h1;
        const float r0 = va[2 * i]     - __uint_as_float(h0);
        const float r1 = va[2 * i + 1] - __uint_as_float(h1);
        lp[i] = (__float_as_uint(r0) >> 16) | (__float_as_uint(r1) & 0xffff0000u);
    }
    *(uint4*)swz16(bH, row, chunk) = make_uint4(hp[0], hp[1], hp[2], hp[3]);
    *(uint4*)swz16(bL, row, chunk) = make_uint4(lp[0], lp[1], lp[2], lp[3]);
}

// RNE-rounded hi-only store (1-MFMA paths).
__device__ __forceinline__ void hi_store8(const float* va,
    unsigned char* bH, int row, int chunk)
{
    unsigned hp[4];
    #pragma unroll
    for (int i = 0; i < 4; i++)
        hp[i] = (unsigned)f2bf(va[2 * i]) | ((unsigned)f2bf(va[2 * i + 1]) << 16);
    *(uint4*)swz16(bH, row, chunk) = make_uint4(hp[0], hp[1], hp[2], hp[3]);
}

// ---- raw loads: NO dependent VALU at issue point (T14 discipline) ----
__device__ __forceinline__ void gload8(float* va, const float* __restrict__ src,
                                       bool ok)
{
    if (ok) {
        const float4 v0 = *(const float4*)(src);
        const float4 v1 = *(const float4*)(src + 4);
        va[0] = v0.x; va[1] = v0.y; va[2] = v0.z; va[3] = v0.w;
        va[4] = v1.x; va[5] = v1.y; va[6] = v1.z; va[7] = v1.w;
    } else {
        #pragma unroll
        for (int i = 0; i < 8; i++) va[i] = 0.f;
    }
}

// raw gathered-embedding load; normalization deferred to commit.
__device__ __forceinline__ void gload_emb8(float* va, const float* __restrict__ erow,
                                           int kb)
{
    if (kb + 8 <= EDIM) {
        const float4 v0 = *(const float4*)(erow + kb);
        const float4 v1 = *(const float4*)(erow + kb + 4);
        va[0] = v0.x; va[1] = v0.y; va[2] = v0.z; va[3] = v0.w;
        va[4] = v1.x; va[5] = v1.y; va[6] = v1.z; va[7] = v1.w;
    } else {
        #pragma unroll
        for (int i = 0; i < 8; i++)
            va[i] = (kb + i < EDIM) ? erow[kb + i] : 0.f;
    }
}

__device__ __forceinline__ void kmask8(float* va, int kbase, int Kvalid)
{
    #pragma unroll
    for (int i = 0; i < 8; i++)
        va[i] = (kbase + i < Kvalid) ? va[i] : 0.f;
}

#define MFMA3(ai, aj) \
    acc[ai][aj] = __builtin_amdgcn_mfma_f32_16x16x32_bf16(fah[ai], fbh[aj], acc[ai][aj], 0, 0, 0); \
    acc[ai][aj] = __builtin_amdgcn_mfma_f32_16x16x32_bf16(fah[ai], fbl[aj], acc[ai][aj], 0, 0, 0); \
    acc[ai][aj] = __builtin_amdgcn_mfma_f32_16x16x32_bf16(fal[ai], fbh[aj], acc[ai][aj], 0, 0, 0);

#define MFMA1(ai, aj) \
    acc[ai][aj] = __builtin_amdgcn_mfma_f32_16x16x32_bf16(fah[ai], fbh[aj], acc[ai][aj], 0, 0, 0);

// ---------------------------------------------------------------------------
// 8-wave (512-thread) geometry: wave covers 64x32 of the 128x128 tile.
//   wr = (wave>>2)*64 row offset; wc = (wave&3)*32 col offset; acc[4][2].
// Staging: sr = tid>>2 (row 0..127), q = tid&3 (16B chunk), 8 elems/thread.
// launch_bounds NOTE: (512,4) cap=128 regs. (512,6) cap=85 < the NM3 loop's
// 88-reg need -> allocator SPILLS the staging path (R6: WRITE_SIZE 129MB ->
// 1.35GB, 4x slower). Do NOT lower the cap below 4.
// ---------------------------------------------------------------------------

// Coalesced transposed store of the 128x128 tile via LDS (stride 129), 512 thr.
__device__ __forceinline__ void store_transposed(
    float* __restrict__ PT, const f32x4 (*acc)[2], float* TR,
    int bn, int Nvalid, int wr, int wc, int lr, int quad, int tid, bool relu)
{
    #pragma unroll
    for (int h = 0; h < 2; h++) {
        __syncthreads();
        if ((wc >> 6) == h) {
            #pragma unroll
            for (int j = 0; j < 2; j++) {
                const int col = (wc & 63) + j * 16 + lr;   // 0..63 within half
                #pragma unroll
                for (int i = 0; i < 4; i++)
                    #pragma unroll
                    for (int r = 0; r < 4; r++) {
                        float v = acc[i][j][r];
                        if (relu) v = fmaxf(v, 0.f);
                        TR[col * 129 + wr + i * 16 + quad * 4 + r] = v;
                    }
            }
        }
        __syncthreads();
        const int row = tid >> 3;                 // 0..63
        const int gp = bn + h * 64 + row;
        if (gp < Nvalid) {
            float* dst = PT + (long long)gp * 128;
            for (int c = (tid & 7); c < 32; c += 8) {
                const int base = row * 129 + c * 4;
                *(float4*)(dst + c * 4) =
                    make_float4(TR[base], TR[base + 1], TR[base + 2], TR[base + 3]);
            }
        }
    }
}

// ---------------------------------------------------------------------------
// Merged phase-A projection GEMM (grid (5,512), 512 thr, XCD-swizzled).
// (512,4): 2 blocks/CU, 16 waves. T14 register prefetch: loads for step t+1
// issued after step t's LDS commit -> in flight across barrier + MFMA.
// ---------------------------------------------------------------------------
__global__ __launch_bounds__(512, 4) void gemm_proj(
    const int* __restrict__ x1, const int* __restrict__ x2,
    const float* __restrict__ emb, const float* __restrict__ norms,
    const u16* __restrict__ W1h, const u16* __restrict__ W1l,
    const u16* __restrict__ W2h, const u16* __restrict__ W2l,
    float* __restrict__ T, float* __restrict__ F0, float* __restrict__ F1)
{
    __shared__ __align__(16) unsigned char smem[33280];   // staging 32KB; TR 33024B

    const int tid = threadIdx.x;
    const int id  = blockIdx.y * 5 + blockIdx.x;
    const int xcd = id & 7;
    const int s   = id >> 3;
    const int mt  = xcd + 8 * (s / 5);
    const int bm  = mt * 128;
    const int bn  = (s % 5) * 128;
    const bool side2 = mt >= 256;
    const bool wb = bn < 256;          // block-uniform precision tier

    const u16* Bh = side2 ? W2h : W1h;
    const u16* Bl = side2 ? W2l : W1l;
    float* F = side2 ? F1 : F0;
    const int fm = side2 ? bm - 32768 : bm;
    const int* toks = (side2 ? x2 - 32768 : x1) + bm;

    const int wave = tid >> 6;
    const int lane = tid & 63;
    const int wr   = (wave >> 2) * 64;
    const int wc   = (wave & 3) * 32;
    const int lr   = lane & 15;
    const int quad = lane >> 4;
    const int sr   = tid >> 2;
    const int q    = tid & 3;
    const int scf  = q * 8;

    const int tok = toks[sr];
    const float nrm = norms[tok];
    const float* erow = emb + (long long)tok * EDIM;

    const int gn = bn + sr;
    const bool bok = gn < 556;
    const u16* Bhp = Bh + (long long)gn * 320 + scf;
    const u16* Blp = Bl + (long long)gn * 320 + scf;

    f32x4 acc[4][2];
    #pragma unroll
    for (int i = 0; i < 4; i++)
        #pragma unroll
        for (int j = 0; j < 2; j++)
            acc[i][j] = (f32x4)(0.0f);

    float av[8];
    uint4 bh, bl;
    gload_emb8(av, erow, scf);
    bh = bok ? *(const uint4*)(Bhp) : make_uint4(0,0,0,0);
    if (wb) bl = bok ? *(const uint4*)(Blp) : make_uint4(0,0,0,0);

    for (int t = 0; t < 10; ++t) {
        // commit staged regs -> LDS (apply nrm here, not at load)
        {
            float sv[8];
            #pragma unroll
            for (int i = 0; i < 8; i++) sv[i] = av[i] * nrm;
            if (wb) split_store8(sv, smem, smem + 8192, sr, q);
            else    hi_store8(sv, smem, sr, q);
            *(uint4*)swz16(smem + 16384, sr, q) = bh;
            if (wb) *(uint4*)swz16(smem + 24576, sr, q) = bl;
        }
        // prefetch next step (stays in flight across barrier + MFMA)
        if (t < 9) {
            gload_emb8(av, erow, (t + 1) * 32 + scf);
            bh = bok ? *(const uint4*)(Bhp + (t + 1) * 32) : make_uint4(0,0,0,0);
            if (wb) bl = bok ? *(const uint4*)(Blp + (t + 1) * 32) : make_uint4(0,0,0,0);
        }
        __syncthreads();

        bf16x8 fah[4], fbh[2];
        #pragma unroll
        for (int i = 0; i < 4; i++)
            fah[i] = *(const bf16x8*)swz16(smem, wr + i * 16 + lr, quad);
        #pragma unroll
        for (int j = 0; j < 2; j++)
            fbh[j] = *(const bf16x8*)swz16(smem + 16384, wc + j * 16 + lr, quad);
        if (wb) {
            bf16x8 fal[4], fbl[2];
            #pragma unroll
            for (int i = 0; i < 4; i++)
                fal[i] = *(const bf16x8*)swz16(smem + 8192, wr + i * 16 + lr, quad);
            #pragma unroll
            for (int j = 0; j < 2; j++)
                fbl[j] = *(const bf16x8*)swz16(smem + 24576, wc + j * 16 + lr, quad);
            #pragma unroll
            for (int i = 0; i < 4; i++)
                #pragma unroll
                for (int j = 0; j < 2; j++) { MFMA3(i, j) }
        } else {
            #pragma unroll
            for (int i = 0; i < 4; i++)
                #pragma unroll
                for (int j = 0; j < 2; j++) { MFMA1(i, j) }
        }
        __syncthreads();
    }

    if (wb) {
        float* Tb = T + (long long)mt * (PDIM * SEQ);
        store_transposed(Tb, acc, (float*)smem, bn, PDIM, wr, wc, lr, quad, tid, false);
    } else {
        #pragma unroll
        for (int i = 0; i < 4; i++) {
            #pragma unroll
            for (int j = 0; j < 2; j++) {
                const int idx = bn + wc + j * 16 + lr - 256;
                if (idx >= EDIM) continue;
                #pragma unroll
                for (int r = 0; r < 4; r++) {
                    const int gm = fm + wr + i * 16 + quad * 4 + r;
                    F[(long long)gm * EDIM + idx] = fmaxf(acc[i][j][r], 0.f);
                }
            }
        }
    }
}

// ---------------------------------------------------------------------------
// Fused xp GEMM (3-MFMA): acc = e @ wp_a (steps 0..9) + probs @ G (10..13).
// grid (2,1,512), 512 thr, (512,4). Unified 14-step prefetched pipeline.
// ---------------------------------------------------------------------------
__global__ __launch_bounds__(512, 4) void gemm_xp(
    const float* __restrict__ P, float* __restrict__ T,
    const int* __restrict__ x1, const int* __restrict__ x2,
    const float* __restrict__ emb, const float* __restrict__ norms,
    const u16* __restrict__ W1h, const u16* __restrict__ W1l,
    const u16* __restrict__ W2h, const u16* __restrict__ W2l,
    float* __restrict__ XCAT)
{
    __shared__ __align__(16) unsigned char smem[33280];

    const int tid = threadIdx.x;
    const int bz  = blockIdx.z;
    const int bn  = blockIdx.x * 128;

    const int wave = tid >> 6;
    const int lane = tid & 63;
    const int wr   = (wave >> 2) * 64;
    const int wc   = (wave & 3) * 32;
    const int lr   = lane & 15;
    const int quad = lane >> 4;
    const int sr   = tid >> 2;
    const int q    = tid & 3;
    const int scf  = q * 8;

    const int* toks = (bz < BATCH) ? x1 + bz * SEQ : x2 + (bz - BATCH) * SEQ;
    const u16* Wh = (bz < BATCH) ? W1h : W2h;
    const u16* Wl = (bz < BATCH) ? W1l : W2l;
    const int tok = toks[sr];
    const float nrm = norms[tok];
    const float* erow = emb + (long long)tok * EDIM;
    const float* Pb = P + (long long)bz * (SEQ * SEQ);
    float* Tb = T + (long long)bz * (PDIM * SEQ);

    const int gn = bn + sr;
    const bool bok = gn < PDIM;
    const u16* Whp = Wh + (long long)gn * 320 + scf;
    const u16* Wlp = Wl + (long long)gn * 320 + scf;
    const float* Pp = Pb + (long long)sr * 128 + scf;
    const float* Tp = Tb + (long long)gn * 128 + scf;

    f32x4 acc[4][2];
    #pragma unroll
    for (int i = 0; i < 4; i++)
        #pragma unroll
        for (int j = 0; j < 2; j++)
            acc[i][j] = (f32x4)(0.0f);

    float av[8], bv[8];
    uint4 bh, bl;

#define XP_LOAD(sidx) do { \
    if ((sidx) < 10) { \
        gload_emb8(av, erow, (sidx) * 32 + scf); \
        bh = bok ? *(const uint4*)(Whp + (sidx) * 32) : make_uint4(0,0,0,0); \
        bl = bok ? *(const uint4*)(Wlp + (sidx) * 32) : make_uint4(0,0,0,0); \
    } else { \
        gload8(av, Pp + ((sidx) - 10) * 32, true); \
        gload8(bv, Tp + ((sidx) - 10) * 32, bok); \
    } \
} while (0)

    XP_LOAD(0);

    for (int t = 0; t < 14; ++t) {
        if (t < 10) {
            float sv[8];
            #pragma unroll
            for (int i = 0; i < 8; i++) sv[i] = av[i] * nrm;
            split_store8(sv, smem, smem + 8192, sr, q);
            *(uint4*)swz16(smem + 16384, sr, q) = bh;
            *(uint4*)swz16(smem + 24576, sr, q) = bl;
        } else {
            split_store8(av, smem,         smem + 8192,  sr, q);
            split_store8(bv, smem + 16384, smem + 24576, sr, q);
        }
        if (t < 13) XP_LOAD(t + 1);
        __syncthreads();

        bf16x8 fah[4], fal[4], fbh[2], fbl[2];
        #pragma unroll
        for (int i = 0; i < 4; i++) {
            fah[i] = *(const bf16x8*)swz16(smem,        wr + i * 16 + lr, quad);
            fal[i] = *(const bf16x8*)swz16(smem + 8192, wr + i * 16 + lr, quad);
        }
        #pragma unroll
        for (int j = 0; j < 2; j++) {
            fbh[j] = *(const bf16x8*)swz16(smem + 16384, wc + j * 16 + lr, quad);
            fbl[j] = *(const bf16x8*)swz16(smem + 24576, wc + j * 16 + lr, quad);
        }
        #pragma unroll
        for (int i = 0; i < 4; i++)
            #pragma unroll
            for (int j = 0; j < 2; j++) { MFMA3(i, j) }
        __syncthreads();
    }
#undef XP_LOAD

    const long long rowbase = (long long)bz * SEQ;
    #pragma unroll
    for (int i = 0; i < 4; i++) {
        #pragma unroll
        for (int j = 0; j < 2; j++) {
            const int gnn = bn + wc + j * 16 + lr;
            if (gnn >= PDIM) continue;
            #pragma unroll
            for (int r = 0; r < 4; r++) {
                const int gm = wr + i * 16 + quad * 4 + r;
                XCAT[(rowbase + gm) * 400 + gnn] = fmaxf(acc[i][j][r], 0.f);
            }
        }
    }
    store_transposed(Tb, acc, (float*)smem, bn, PDIM, wr, wc, lr, quad, tid, true);
}

// ---------------------------------------------------------------------------
// Flat split-bf16 MFMA GEMM. NM = 3 (split) or 1 (plain bf16 RNE). 512 thr.
// (512,4) + T14 register prefetch.
// ---------------------------------------------------------------------------
template <int NM>
__global__ __launch_bounds__(512, 4) void gemm_flat(
    const float* __restrict__ A,
    const u16* __restrict__ Bh, const u16* __restrict__ Bl,
    const u16* __restrict__ Bh2, const u16* __restrict__ Bl2, int Msplit,
    float* __restrict__ C, float* __restrict__ PO, const int* __restrict__ sizes,
    int M, int N, int Kp, int lda, int ldb, int ldc, int flags)
{
    constexpr int BOFF = (NM == 3) ? 16384 : 8192;
    __shared__ __align__(16) unsigned char smem[(NM == 3) ? 32768 : 16384];

    const int tid = threadIdx.x;
    int bx = blockIdx.x, by = blockIdx.y;
    if ((gridDim.y & 7) == 0) {
        const int gx = gridDim.x;
        const int id = by * gx + bx;
        const int xcd = id & 7;
        const int s = id >> 3;
        by = xcd + 8 * (s / gx);
        bx = s % gx;
    }
    const int bm = by * 128;
    const int bn = bx * 128;

    const int wave = tid >> 6;
    const int lane = tid & 63;
    const int wr   = (wave >> 2) * 64;
    const int wc   = (wave & 3) * 32;
    const int lr   = lane & 15;
    const int quad = lane >> 4;
    const int sr   = tid >> 2;
    const int q    = tid & 3;
    const int scf  = q * 8;

    if (bm >= Msplit) { Bh = Bh2; Bl = Bl2; }

    const float* Ap = A + (long long)(bm + sr) * lda + scf;
    const int gn = bn + sr;
    const bool bok = gn < N;
    const u16* Bhp = Bh + (long long)gn * ldb + scf;
    const u16* Blp = Bl + (long long)gn * ldb + scf;

    f32x4 acc[4][2];
    #pragma unroll
    for (int i = 0; i < 4; i++)
        #pragma unroll
        for (int j = 0; j < 2; j++)
            acc[i][j] = (f32x4)(0.0f);

    const int NT = Kp >> 5;
    float av[8];
    uint4 bh, bl;
    gload8(av, Ap, true);
    bh = bok ? *(const uint4*)(Bhp) : make_uint4(0,0,0,0);
    if constexpr (NM == 3) bl = bok ? *(const uint4*)(Blp) : make_uint4(0,0,0,0);

    for (int t = 0; t < NT; ++t) {
        if constexpr (NM == 3) {
            split_store8(av, smem, smem + 8192, sr, q);
            *(uint4*)swz16(smem + BOFF,        sr, q) = bh;
            *(uint4*)swz16(smem + BOFF + 8192, sr, q) = bl;
        } else {
            hi_store8(av, smem, sr, q);
            *(uint4*)swz16(smem + BOFF, sr, q) = bh;
        }
        if (t < NT - 1) {
            gload8(av, Ap + (t + 1) * 32, true);
            bh = bok ? *(const uint4*)(Bhp + (t + 1) * 32) : make_uint4(0,0,0,0);
            if constexpr (NM == 3)
                bl = bok ? *(const uint4*)(Blp + (t + 1) * 32) : make_uint4(0,0,0,0);
        }
        __syncthreads();

        bf16x8 fah[4], fbh[2];
        #pragma unroll
        for (int i = 0; i < 4; i++)
            fah[i] = *(const bf16x8*)swz16(smem, wr + i * 16 + lr, quad);
        #pragma unroll
        for (int j = 0; j < 2; j++)
            fbh[j] = *(const bf16x8*)swz16(smem + BOFF, wc + j * 16 + lr, quad);
        if constexpr (NM == 3) {
            bf16x8 fal[4], fbl[2];
            #pragma unroll
            for (int i = 0; i < 4; i++)
                fal[i] = *(const bf16x8*)swz16(smem + 8192, wr + i * 16 + lr, quad);
            #pragma unroll
            for (int j = 0; j < 2; j++)
                fbl[j] = *(const bf16x8*)swz16(smem + BOFF + 8192, wc + j * 16 + lr, quad);
            #pragma unroll
            for (int i = 0; i < 4; i++)
                #pragma unroll
                for (int j = 0; j < 2; j++) { MFMA3(i, j) }
        } else {
            #pragma unroll
            for (int i = 0; i < 4; i++)
                #pragma unroll
                for (int j = 0; j < 2; j++) { MFMA1(i, j) }
        }
        __syncthreads();
    }

    const int sz = PO ? sizes[bm >> 7] : 0;
    float ps[2] = {0.f, 0.f};
    #pragma unroll
    for (int j = 0; j < 2; j++) {
        const int gnn = bn + wc + j * 16 + lr;
        const bool gok = gnn < N;
        #pragma unroll
        for (int i = 0; i < 4; i++) {
            #pragma unroll
            for (int r = 0; r < 4; r++) {
                const int row = wr + i * 16 + quad * 4 + r;
                const int gm = bm + row;
                float v = acc[i][j][r];
                if (flags & F_RELU) v = fmaxf(v, 0.f);
                if (gok && C) C[(long long)gm * ldc + gnn] = v;
                if (PO && row < sz) ps[j] += v;
            }
        }
    }
    if (PO) {
        #pragma unroll
        for (int j = 0; j < 2; j++) {
            ps[j] += __shfl_xor(ps[j], 16);
            ps[j] += __shfl_xor(ps[j], 32);
        }
        float* PS = (float*)smem;
        __syncthreads();
        if (wr == 0 && quad == 0) {
            #pragma unroll
            for (int j = 0; j < 2; j++) PS[wc + j * 16 + lr] = ps[j];
        }
        __syncthreads();
        if (wr == 64 && quad == 0) {
            #pragma unroll
            for (int j = 0; j < 2; j++) PS[wc + j * 16 + lr] += ps[j];
        }
        __syncthreads();
        if (tid < 128) {
            const int gnn = bn + tid;
            if (gnn < N) PO[(long long)(bm >> 7) * N + gnn] = PS[tid];
        }
    }
}

// ---------------------------------------------------------------------------
// Batched MFMA GEMM, NT layout, 512 thr, (512,4) for MODE 0, (512,2) else.
// MODE 0 (3-MFMA split); MODE 1 (att: dist-bias + row softmax);
// MODE 2 (sim: mask + row softmax -> C + col softmax^T -> PT).
// T14 prefetch (kmask deferred to commit). Softmax scratch stride 132.
// ---------------------------------------------------------------------------
#define SLD 132
template <int MODE>
__global__ __launch_bounds__(512, (MODE == 0) ? 4 : 2) void gemm_bat(
    const float* __restrict__ A, const float* __restrict__ Aalt,
    const float* __restrict__ B, const float* __restrict__ Balt,
    float* __restrict__ C, float* __restrict__ PT,
    int N, int Kvalid, int Kp, int lda, int ldb, int ldc,
    long long sA, long long sB, long long sC, long long sPT,
    int flags, const float* __restrict__ bias_ptr, const int* __restrict__ sizes,
    int same_ab)
{
    constexpr int NM = (MODE == 0) ? 3 : 1;
    constexpr int BOFF = (NM == 3) ? 16384 : 8192;
    constexpr int SMB  = (MODE == 0) ? 32768 : (128 * SLD * 4);  // 67584
    __shared__ __align__(16) unsigned char smem[SMB];

    const int bz = blockIdx.z;
    long long zb = bz;
    const float* Ause = A;
    const float* Buse = B;
    if (Aalt && bz >= BATCH) { Ause = Aalt; Buse = Balt; zb = bz - BATCH; }
    Ause += zb * sA;
    Buse += zb * sB;
    C += (long long)bz * sC;
    if (PT) PT += (long long)bz * sPT;

    const int tid  = threadIdx.x;
    const int bn   = blockIdx.x * 128;
    const int wave = tid >> 6;
    const int lane = tid & 63;
    const int wr   = (wave >> 2) * 64;
    const int wc   = (wave & 3) * 32;
    const int lr   = lane & 15;
    const int quad = lane >> 4;
    const int sr   = tid >> 2;
    const int q    = tid & 3;
    const int scf  = q * 8;

    f32x4 acc[4][2];
    #pragma unroll
    for (int i = 0; i < 4; i++)
        #pragma unroll
        for (int j = 0; j < 2; j++)
            acc[i][j] = (f32x4)(0.0f);

    const float* Apt = Ause + (long long)sr * lda + scf;
    const int gn = bn + sr;
    const bool bok = gn < N;
    const float* Bpt = Buse + (long long)gn * ldb + scf;

    const int NT = Kp >> 5;
    float av[8], bv[8];
    gload8(av, Apt, true);
    if (!same_ab) gload8(bv, Bpt, bok);

    for (int t = 0; t < NT; ++t) {
        kmask8(av, t * 32 + scf, Kvalid);
        if constexpr (NM == 3) split_store8(av, smem, smem + 8192, sr, q);
        else                   hi_store8(av, smem, sr, q);
        if (!same_ab) {
            kmask8(bv, t * 32 + scf, Kvalid);
            if constexpr (NM == 3) split_store8(bv, smem + BOFF, smem + BOFF + 8192, sr, q);
            else                   hi_store8(bv, smem + BOFF, sr, q);
        }
        if (t < NT - 1) {
            gload8(av, Apt + (t + 1) * 32, true);
            if (!same_ab) gload8(bv, Bpt + (t + 1) * 32, bok);
        }
        __syncthreads();

        unsigned char* rbB = same_ab ? smem : smem + BOFF;
        bf16x8 fah[4], fbh[2];
        #pragma unroll
        for (int i = 0; i < 4; i++)
            fah[i] = *(const bf16x8*)swz16(smem, wr + i * 16 + lr, quad);
        #pragma unroll
        for (int j = 0; j < 2; j++)
            fbh[j] = *(const bf16x8*)swz16(rbB, wc + j * 16 + lr, quad);
        if constexpr (NM == 3) {
            bf16x8 fal[4], fbl[2];
            #pragma unroll
            for (int i = 0; i < 4; i++)
                fal[i] = *(const bf16x8*)swz16(smem + 8192, wr + i * 16 + lr, quad);
            #pragma unroll
            for (int j = 0; j < 2; j++)
                fbl[j] = *(const bf16x8*)swz16(rbB + 8192, wc + j * 16 + lr, quad);
            #pragma unroll
            for (int i = 0; i < 4; i++)
                #pragma unroll
                for (int j = 0; j < 2; j++) { MFMA3(i, j) }
        } else {
            #pragma unroll
            for (int i = 0; i < 4; i++)
                #pragma unroll
                for (int j = 0; j < 2; j++) { MFMA1(i, j) }
        }
        __syncthreads();
    }

    if (MODE == 1) {
        float* S = (float*)smem;
        const float bias = bias_ptr[0];
        #pragma unroll
        for (int i = 0; i < 4; i++) {
            #pragma unroll
            for (int j = 0; j < 2; j++) {
                const int col = wc + j * 16 + lr;
                #pragma unroll
                for (int r = 0; r < 4; r++) {
                    const int row = wr + i * 16 + quad * 4 + r;
                    int d = row - col; d = d < 0 ? -d : d;
                    S[row * SLD + col] = acc[i][j][r] + ((d >= 10) ? bias : 0.f);
                }
            }
        }
        __syncthreads();
        const int row = tid >> 2;
        const int qd  = (tid & 3) * 32;
        float* Sr = S + row * SLD + qd;
        float mx = -1e30f;
        #pragma unroll
        for (int c = 0; c < 8; c++) {
            const float4 v = *(const float4*)(Sr + c * 4);
            mx = fmaxf(fmaxf(fmaxf(mx, v.x), fmaxf(v.y, v.z)), v.w);
        }
        mx = fmaxf(mx, __shfl_xor(mx, 1));
        mx = fmaxf(mx, __shfl_xor(mx, 2));
        float sum = 0.f;
        #pragma unroll
        for (int c = 0; c < 8; c++) {
            float4 v = *(const float4*)(Sr + c * 4);
            v.x = __expf(v.x - mx); v.y = __expf(v.y - mx);
            v.z = __expf(v.z - mx); v.w = __expf(v.w - mx);
            sum += (v.x + v.y) + (v.z + v.w);
            *(float4*)(Sr + c * 4) = v;
        }
        sum += __shfl_xor(sum, 1);
        sum += __shfl_xor(sum, 2);
        const float inv = 1.f / sum;
        #pragma unroll
        for (int c = 0; c < 8; c++) {
            float4 v = *(const float4*)(Sr + c * 4);
            v.x *= inv; v.y *= inv; v.z *= inv; v.w *= inv;
            *(float4*)&C[(long long)row * ldc + qd + c * 4] = v;
        }
    } else if (MODE == 2) {
        float* S = (float*)smem;
        const int s1 = sizes[bz];
        const int s2 = sizes[BATCH + bz];
        #pragma unroll
        for (int i = 0; i < 4; i++) {
            #pragma unroll
            for (int j = 0; j < 2; j++) {
                const int col = wc + j * 16 + lr;
                #pragma unroll
                for (int r = 0; r < 4; r++) {
                    const int row = wr + i * 16 + quad * 4 + r;
                    float v = acc[i][j][r];
                    if (row >= s1 || col >= s2) v = 0.f;
                    S[row * SLD + col] = v;
                }
            }
        }
        __syncthreads();
        const int row = tid >> 2;
        const int qd  = (tid & 3) * 32;
        {
            // row softmax (no writeback: column pass needs original S)
            const float* Sr = S + row * SLD + qd;
            float mx = -1e30f;
            #pragma unroll
            for (int c = 0; c < 8; c++) {
                const float4 v = *(const float4*)(Sr + c * 4);
                mx = fmaxf(fmaxf(fmaxf(mx, v.x), fmaxf(v.y, v.z)), v.w);
            }
            mx = fmaxf(mx, __shfl_xor(mx, 1));
            mx = fmaxf(mx, __shfl_xor(mx, 2));
            float sum = 0.f;
            #pragma unroll
            for (int c = 0; c < 8; c++) {
                const float4 v = *(const float4*)(Sr + c * 4);
                sum += (__expf(v.x - mx) + __expf(v.y - mx))
                     + (__expf(v.z - mx) + __expf(v.w - mx));
            }
            sum += __shfl_xor(sum, 1);
            sum += __shfl_xor(sum, 2);
            const float inv = 1.f / sum;
            #pragma unroll
            for (int c = 0; c < 8; c++) {
                const float4 v = *(const float4*)(Sr + c * 4);
                float4 o;
                o.x = __expf(v.x - mx) * inv; o.y = __expf(v.y - mx) * inv;
                o.z = __expf(v.z - mx) * inv; o.w = __expf(v.w - mx) * inv;
                *(float4*)&C[(long long)row * 128 + qd + c * 4] = o;
            }
        }
        {
            // column softmax -> PT (column = tid>>2, rows qd..qd+31)
            const int colx = row;
            float mx = -1e30f;
            for (int r = 0; r < 32; r++)
                mx = fmaxf(mx, S[(qd + r) * SLD + colx]);
            mx = fmaxf(mx, __shfl_xor(mx, 1));
            mx = fmaxf(mx, __shfl_xor(mx, 2));
            float sum = 0.f;
            for (int r = 0; r < 32; r++)
                sum += __expf(S[(qd + r) * SLD + colx] - mx);
            sum += __shfl_xor(sum, 1);
            sum += __shfl_xor(sum, 2);
            const float inv = 1.f / sum;
            #pragma unroll
            for (int r4 = 0; r4 < 8; r4++) {
                float4 o;
                o.x = __expf(S[(qd + r4 * 4 + 0) * SLD + colx] - mx) * inv;
                o.y = __expf(S[(qd + r4 * 4 + 1) * SLD + colx] - mx) * inv;
                o.z = __expf(S[(qd + r4 * 4 + 2) * SLD + colx] - mx) * inv;
                o.w = __expf(S[(qd + r4 * 4 + 3) * SLD + colx] - mx) * inv;
                *(float4*)&PT[(long long)colx * 128 + qd + r4 * 4] = o;
            }
        }
    } else {
        const int s1 = sizes ? sizes[bz] : SEQ;
        const int s2 = sizes ? sizes[BATCH + bz] : SEQ;
        #pragma unroll
        for (int i = 0; i < 4; i++) {
            #pragma unroll
            for (int j = 0; j < 2; j++) {
                const int gnn = bn + wc + j * 16 + lr;
                if (gnn >= N) continue;
                #pragma unroll
                for (int r = 0; r < 4; r++) {
                    const int gm = wr + i * 16 + quad * 4 + r;
                    float v = acc[i][j][r];
                    if (sizes && (gm >= s1 || gnn >= s2)) v = 0.f;
                    if (flags & F_ACCUM) v += C[(long long)gm * ldc + gnn];
                    if (flags & F_RELU)  v = fmaxf(v, 0.f);
                    C[(long long)gm * ldc + gnn] = v;
                    if (PT) PT[(long long)gnn * 128 + gm] = v;
                }
            }
        }
    }
}

// All weight transposes + hi/lo splits in one launch.
struct WEnt { const float* src; u16* H; u16* L; int K, N, Kp, rowStart; };
struct WTab { WEnt e[11]; };
__global__ void convert_all(WTab t)
{
    const int row = blockIdx.y;
    const int k = blockIdx.x * 256 + threadIdx.x;
    #pragma unroll
    for (int s = 0; s < 11; s++) {
        const WEnt w = t.e[s];
        if (row >= w.rowStart && row < w.rowStart + w.N) {
            const int n = row - w.rowStart;
            if (k < w.Kp) {
                const float v = (k < w.K) ? w.src[(long long)k * w.N + n] : 0.f;
                const u16 h = f2bf(v);
                w.H[(long long)n * w.Kp + k] = h;
                w.L[(long long)n * w.Kp + k] = f2bf(v - bf2f(h));
            }
            return;
        }
    }
}

__global__ void norms_kernel(const float* __restrict__ emb, float* __restrict__ norms)
{
    const int r = blockIdx.x;
    const int lane = threadIdx.x;
    const float* row = emb + (long long)r * EDIM;
    float ss = 0.f;
    #pragma unroll
    for (int i = 0; i < 5; i++) {
        const int c = lane + i * 64;
        const float f = (c < EDIM) ? row[c] : 0.f;
        ss += f * f;
    }
    #pragma unroll
    for (int o = 32; o > 0; o >>= 1) ss += __shfl_xor(ss, o);
    if (lane == 0) norms[r] = rsqrtf(fmaxf(ss, 1e-12f));
}

__global__ void sizes_kernel(const int* __restrict__ x1, const int* __restrict__ x2,
                             int* __restrict__ sizes)
{
    const int b = blockIdx.x;
    const int side = blockIdx.y;
    const int* x = (side ? x2 : x1) + b * SEQ;
    const int nz = (x[threadIdx.x] != 0) ? 1 : 0;
    const unsigned long long bal = __ballot(nz);
    __shared__ int part[2];
    if ((threadIdx.x & 63) == 0) part[threadIdx.x >> 6] = __popcll(bal);
    __syncthreads();
    if (threadIdx.x == 0) sizes[side * BATCH + b] = part[0] + part[1];
}

__global__ void agg_kernel(const float* __restrict__ v1s, const float* __restrict__ v2s,
                           const float* __restrict__ w_agg, float* __restrict__ y)
{
    const int b = blockIdx.x;
    const int lane = threadIdx.x;
    float a0 = 0.f, a1 = 0.f, a2 = 0.f;
    for (int k = lane; k < 800; k += 64) {
        const float v = (k < 400) ? v1s[b * 400 + k] : v2s[b * 400 + k - 400];
        a0 = fmaf(v, w_agg[k * 3 + 0], a0);
        a1 = fmaf(v, w_agg[k * 3 + 1], a1);
        a2 = fmaf(v, w_agg[k * 3 + 2], a2);
    }
    #pragma unroll
    for (int o = 32; o > 0; o >>= 1) {
        a0 += __shfl_xor(a0, o);
        a1 += __shfl_xor(a1, o);
        a2 += __shfl_xor(a2, o);
    }
    if (lane == 0) {
        y[b * 3 + 0] = fmaxf(a0, 0.f);
        y[b * 3 + 1] = fmaxf(a1, 0.f);
        y[b * 3 + 2] = fmaxf(a2, 0.f);
    }
}

extern "C" void kernel_launch(void* const* d_in, const int* in_sizes, int n_in,
                              void* d_out, int out_size, void* d_ws, size_t ws_size,
                              hipStream_t stream)
{
    (void)in_sizes; (void)n_in; (void)out_size; (void)ws_size;
    const int*   x1         = (const int*)d_in[0];
    const int*   x2         = (const int*)d_in[1];
    const float* emb        = (const float*)d_in[2];
    const float* w_intra    = (const float*)d_in[3];
    const float* bias_intra = (const float*)d_in[4];
    const float* w_proj1    = (const float*)d_in[5];
    const float* w_proj2    = (const float*)d_in[6];
    const float* w_att      = (const float*)d_in[7];
    const float* w_cmp1     = (const float*)d_in[8];
    const float* w_cmp2     = (const float*)d_in[9];
    const float* w_agg      = (const float*)d_in[10];
    float* y  = (float*)d_out;
    float* ws = (float*)d_ws;

    // ---- workspace (floats); total ~58.64M fl = 234.6 MB ----
    float* X1CAT = ws;                        // [32768,400]: x1p | beta; phase A: F side-2
    float* X2CAT = X1CAT + 13107200;          // [32768,400]: x2p | alpha (contig)
    float* T     = X2CAT + 13107200;          // [512,200,128]: G^T -> x_proj^T
    float* FBUF  = T + 13107200;              // [32768,300] intra f side-1
    float* ATT   = FBUF + 9830400;            // [512,128,128] probs (dead after xp)
    float* POOL  = ATT + 8388608;             // [512,400] pooled v1|v2
    int*   SIZES = (int*)(POOL + 204800);     // [2,256] + pad
    float* NORMS = (float*)(SIZES + 512);     // [32000] + pad
    u16*   W1H   = (u16*)(NORMS + 32768);     // side-1 stack [556][320]: wp_b|z56|intra
    u16*   W1L   = W1H + 177920;
    u16*   W2H   = W1L + 177920;              // side-2 stack [556][320]
    u16*   W2L   = W2H + 177920;
    u16*   WAH   = W2L + 177920;              // w_att^T  [200][224]
    u16*   WAL   = WAH + 44800;
    u16*   WC1H  = WAL + 44800;               // w_cmp1^T [400][416]
    u16*   WC1L  = WC1H + 166400;
    u16*   WC2H  = WC1L + 166400;
    u16*   WC2L  = WC2H + 166400;
    u16*   WPA1H = WC2L + 166400;             // wp_a side1 [200][320]
    u16*   WPA1L = WPA1H + 64000;
    u16*   WPA2H = WPA1L + 64000;
    u16*   WPA2L = WPA2H + 64000;

    // phase-A alias: side-2 intra f lives in X1CAT region (dead until xp)
    float* F1X = X1CAT;                       // [32768,300]
    // phase-B aliases: F12 spans FBUF + head of ATT (probs dead by then)
    float* F12 = FBUF;                        // [65536,200] f1|f2
    float* F2  = FBUF + 6553600;
    // sim outputs alias the f slots they consumed (block-local WAR only):
    float* SIMP = F2;                         // probs slot bz at F2  + bz*25600
    float* SMTP = F12;                        // probs^T slot bz at F12 + bz*25600
    float* T1  = T;
    float* T2  = T + 6553600;

    const long long sbSS = (long long)SEQ * SEQ;     // 16384
    const long long sbF  = (long long)SEQ * EDIM;    // 38400
    const long long sbFP = 25600;                    // f1/f2 slot stride (128*200)
    const long long sbC  = (long long)SEQ * 400;     // 51200
    const long long sbT  = (long long)PDIM * SEQ;    // 25600

    sizes_kernel<<<dim3(BATCH, 2), 128, 0, stream>>>(x1, x2, SIZES);
    norms_kernel<<<32000, 64, 0, stream>>>(emb, NORMS);

    {
        WTab t;
        t.e[0]  = { w_proj1 + 300 * 200, W1H,             W1L,             300, 200, 320, 0    };
        t.e[1]  = { w_intra,             W1H + 200 * 320, W1L + 200 * 320,   0,  56, 320, 200  };
        t.e[2]  = { w_intra,             W1H + 256 * 320, W1L + 256 * 320, 300, 300, 320, 256  };
        t.e[3]  = { w_proj2 + 300 * 200, W2H,             W2L,             300, 200, 320, 556  };
        t.e[4]  = { w_intra,             W2H + 200 * 320, W2L + 200 * 320,   0,  56, 320, 756  };
        t.e[5]  = { w_intra,             W2H + 256 * 320, W2L + 256 * 320, 300, 300, 320, 812  };
        t.e[6]  = { w_att,               WAH,             WAL,             200, 200, 224, 1112 };
        t.e[7]  = { w_cmp1,              WC1H,            WC1L,            400, 400, 416, 1312 };
        t.e[8]  = { w_cmp2,              WC2H,            WC2L,            400, 400, 416, 1712 };
        t.e[9]  = { w_proj1,             WPA1H,           WPA1L,           300, 200, 320, 2112 };
        t.e[10] = { w_proj2,             WPA2H,           WPA2L,           300, 200, 320, 2312 };
        convert_all<<<dim3(2, 2512), 256, 0, stream>>>(t);
    }

    // -------- phase A --------
    // merged proj (both sides): T[0:512] = (e@wp_b)^T; f side1 -> FBUF, side2 -> F1X
    gemm_proj<<<dim3(5, 512), 512, 0, stream>>>(
        x1, x2, emb, NORMS, W1H, W1L, W2H, W2L, T, FBUF, F1X);
    // merged att (512 batches, 1-MFMA): probs = rowsoftmax(f f^T + dbias) -> ATT
    gemm_bat<1><<<dim3(1, 1, 2 * BATCH), 512, 0, stream>>>(
        FBUF, F1X, FBUF, nullptr, ATT, nullptr,
        SEQ, EDIM, 320, EDIM, EDIM, SEQ, sbF, sbF, sbSS, 0,
        0, bias_intra, nullptr, 1);
    // fused xp (3-MFMA): XCAT[:,0:200] = relu(e@wp_a + probs@G); x_proj^T -> T
    gemm_xp<<<dim3(2, 1, 2 * BATCH), 512, 0, stream>>>(
        ATT, T, x1, x2, emb, NORMS, WPA1H, WPA1L, WPA2H, WPA2L, X1CAT);

    // -------- phase B --------
    // f1|f2 = relu(x_proj @ w_att)  [1-MFMA; A cols 200:224 garbage*0]
    gemm_flat<1><<<dim3(2, 512), 512, 0, stream>>>(
        X1CAT, WAH, WAL, WAH, WAL, 1 << 30, F12, nullptr, nullptr,
        2 * BSTOK, PDIM, 224, 400, 224, PDIM, F_RELU);
    // fused sim (1-MFMA): mask(f1 f2^T) -> rowsm over f2 slot + colsm^T over f1 slot
    gemm_bat<2><<<dim3(1, 1, BATCH), 512, 0, stream>>>(
        F12, nullptr, F2, nullptr, SIMP, SMTP,
        SEQ, PDIM, 224, PDIM, PDIM, SEQ, sbFP, sbFP, sbFP, sbFP,
        0, nullptr, SIZES, 0);
    // beta (bz<256) / alpha (bz>=256) -> X1CAT/X2CAT cols 200:400  [3-MFMA]
    gemm_bat<0><<<dim3(2, 1, 2 * BATCH), 512, 0, stream>>>(
        SIMP, SMTP, T2, T1, X1CAT + 200, nullptr,
        PDIM, SEQ, SEQ, SEQ, SEQ, 400, sbFP, sbT, sbC, 0,
        0, nullptr, nullptr, 0);

    // -------- phase C: fused compare + masked pool, aggregate [3-MFMA] --------
    gemm_flat<3><<<dim3(4, 512), 512, 0, stream>>>(
        X1CAT, WC1H, WC1L, WC2H, WC2L, BSTOK,
        nullptr, POOL, SIZES,
        2 * BSTOK, 400, 416, 400, 416, 400, F_RELU);
    agg_kernel<<<BATCH, 64, 0, stream>>>(POOL, POOL + 102400, w_agg, y);
}

// Round 8
// 461.966 us; speedup vs baseline: 1.6822x; 1.0002x over previous
//
#include <hip/hip_runtime.h>

#define BATCH 256
#define SEQ   128
#define EDIM  300
#define PDIM  200
#define BSTOK (BATCH * SEQ)

#define F_RELU  1
#define F_ACCUM 2

typedef unsigned short u16;
typedef __attribute__((ext_vector_type(8))) short bf16x8;
typedef __attribute__((ext_vector_type(4))) float f32x4;

__device__ __forceinline__ u16 f2bf(float x) {
    unsigned u = __float_as_uint(x);
    unsigned r = u + 0x7fffu + ((u >> 16) & 1u);
    return (u16)(r >> 16);
}
__device__ __forceinline__ float bf2f(u16 h) {
    return __uint_as_float(((unsigned)h) << 16);
}

// ---------------------------------------------------------------------------
// Swizzled [128][32]-u16 LDS tile: 64B rows, 16B chunks, chunk XOR (row>>1)&3.
// 8KB per tile. Applied on BOTH write and read.
// ---------------------------------------------------------------------------
__device__ __forceinline__ unsigned char* swz16(unsigned char* base, int row, int chunk) {
    return base + row * 64 + (((chunk ^ (row >> 1)) & 3) << 4);
}

// 8 fp32 -> hi(trunc)/lo(residual) bf16, one 16B chunk each.
__device__ __forceinline__ void split_store8(const float* va,
    unsigned char* bH, unsigned char* bL, int row, int chunk)
{
    unsigned hp[4], lp[4];
    #pragma unroll
    for (int i = 0; i < 4; i++) {
        const unsigned u0 = __float_as_uint(va[2 * i]);
        const unsigned u1 = __float_as_uint(va[2 * i + 1]);
        const unsigned h0 = u0 & 0xffff0000u;
        const unsigned h1 = u1 & 0xffff0000u;
        hp[i] = (u0 >> 16) | h1;
        const float r0 = va[2 * i]     - __uint_as_float(h0);
        const float r1 = va[2 * i + 1] - __uint_as_float(h1);
        lp[i] = (__float_as_uint(r0) >> 16) | (__float_as_uint(r1) & 0xffff0000u);
    }
    *(uint4*)swz16(bH, row, chunk) = make_uint4(hp[0], hp[1], hp[2], hp[3]);
    *(uint4*)swz16(bL, row, chunk) = make_uint4(lp[0], lp[1], lp[2], lp[3]);
}

// RNE-rounded hi-only store (1-MFMA paths).
__device__ __forceinline__ void hi_store8(const float* va,
    unsigned char* bH, int row, int chunk)
{
    unsigned hp[4];
    #pragma unroll
    for (int i = 0; i < 4; i++)
        hp[i] = (unsigned)f2bf(va[2 * i]) | ((unsigned)f2bf(va[2 * i + 1]) << 16);
    *(uint4*)swz16(bH, row, chunk) = make_uint4(hp[0], hp[1], hp[2], hp[3]);
}

// ---- raw loads: NO dependent VALU at issue point (T14 discipline) ----
__device__ __forceinline__ void gload8(float* va, const float* __restrict__ src,
                                       bool ok)
{
    if (ok) {
        const float4 v0 = *(const float4*)(src);
        const float4 v1 = *(const float4*)(src + 4);
        va[0] = v0.x; va[1] = v0.y; va[2] = v0.z; va[3] = v0.w;
        va[4] = v1.x; va[5] = v1.y; va[6] = v1.z; va[7] = v1.w;
    } else {
        #pragma unroll
        for (int i = 0; i < 8; i++) va[i] = 0.f;
    }
}

// raw gathered-embedding load; normalization deferred to commit.
__device__ __forceinline__ void gload_emb8(float* va, const float* __restrict__ erow,
                                           int kb)
{
    if (kb + 8 <= EDIM) {
        const float4 v0 = *(const float4*)(erow + kb);
        const float4 v1 = *(const float4*)(erow + kb + 4);
        va[0] = v0.x; va[1] = v0.y; va[2] = v0.z; va[3] = v0.w;
        va[4] = v1.x; va[5] = v1.y; va[6] = v1.z; va[7] = v1.w;
    } else {
        #pragma unroll
        for (int i = 0; i < 8; i++)
            va[i] = (kb + i < EDIM) ? erow[kb + i] : 0.f;
    }
}

__device__ __forceinline__ void kmask8(float* va, int kbase, int Kvalid)
{
    #pragma unroll
    for (int i = 0; i < 8; i++)
        va[i] = (kbase + i < Kvalid) ? va[i] : 0.f;
}

#define MFMA3(ai, aj) \
    acc[ai][aj] = __builtin_amdgcn_mfma_f32_16x16x32_bf16(fah[ai], fbh[aj], acc[ai][aj], 0, 0, 0); \
    acc[ai][aj] = __builtin_amdgcn_mfma_f32_16x16x32_bf16(fah[ai], fbl[aj], acc[ai][aj], 0, 0, 0); \
    acc[ai][aj] = __builtin_amdgcn_mfma_f32_16x16x32_bf16(fal[ai], fbh[aj], acc[ai][aj], 0, 0, 0);

#define MFMA1(ai, aj) \
    acc[ai][aj] = __builtin_amdgcn_mfma_f32_16x16x32_bf16(fah[ai], fbh[aj], acc[ai][aj], 0, 0, 0);

// ---------------------------------------------------------------------------
// 8-wave (512-thread) geometry: wave covers 64x32 of the 128x128 tile.
//   wr = (wave>>2)*64 row offset; wc = (wave&3)*32 col offset; acc[4][2].
// Staging: sr = tid>>2 (row 0..127), q = tid&3 (16B chunk), 8 elems/thread.
// launch_bounds NOTE: (512,4) cap=128 regs. (512,6) cap=85 < the NM3 loop's
// 88-reg need -> allocator SPILLS the staging path (R6: WRITE_SIZE 129MB ->
// 1.35GB, 4x slower). Do NOT lower the cap below 4.
// ---------------------------------------------------------------------------

// Coalesced transposed store of the 128x128 tile via LDS (stride 129), 512 thr.
__device__ __forceinline__ void store_transposed(
    float* __restrict__ PT, const f32x4 (*acc)[2], float* TR,
    int bn, int Nvalid, int wr, int wc, int lr, int quad, int tid, bool relu)
{
    #pragma unroll
    for (int h = 0; h < 2; h++) {
        __syncthreads();
        if ((wc >> 6) == h) {
            #pragma unroll
            for (int j = 0; j < 2; j++) {
                const int col = (wc & 63) + j * 16 + lr;   // 0..63 within half
                #pragma unroll
                for (int i = 0; i < 4; i++)
                    #pragma unroll
                    for (int r = 0; r < 4; r++) {
                        float v = acc[i][j][r];
                        if (relu) v = fmaxf(v, 0.f);
                        TR[col * 129 + wr + i * 16 + quad * 4 + r] = v;
                    }
            }
        }
        __syncthreads();
        const int row = tid >> 3;                 // 0..63
        const int gp = bn + h * 64 + row;
        if (gp < Nvalid) {
            float* dst = PT + (long long)gp * 128;
            for (int c = (tid & 7); c < 32; c += 8) {
                const int base = row * 129 + c * 4;
                *(float4*)(dst + c * 4) =
                    make_float4(TR[base], TR[base + 1], TR[base + 2], TR[base + 3]);
            }
        }
    }
}

// ---------------------------------------------------------------------------
// Merged phase-A projection GEMM (grid (5,512), 512 thr, XCD-swizzled).
// (512,4): 2 blocks/CU, 16 waves. T14 register prefetch: loads for step t+1
// issued after step t's LDS commit -> in flight across barrier + MFMA.
// ---------------------------------------------------------------------------
__global__ __launch_bounds__(512, 4) void gemm_proj(
    const int* __restrict__ x1, const int* __restrict__ x2,
    const float* __restrict__ emb, const float* __restrict__ norms,
    const u16* __restrict__ W1h, const u16* __restrict__ W1l,
    const u16* __restrict__ W2h, const u16* __restrict__ W2l,
    float* __restrict__ T, float* __restrict__ F0, float* __restrict__ F1)
{
    __shared__ __align__(16) unsigned char smem[33280];   // staging 32KB; TR 33024B

    const int tid = threadIdx.x;
    const int id  = blockIdx.y * 5 + blockIdx.x;
    const int xcd = id & 7;
    const int s   = id >> 3;
    const int mt  = xcd + 8 * (s / 5);
    const int bm  = mt * 128;
    const int bn  = (s % 5) * 128;
    const bool side2 = mt >= 256;
    const bool wb = bn < 256;          // block-uniform precision tier

    const u16* Bh = side2 ? W2h : W1h;
    const u16* Bl = side2 ? W2l : W1l;
    float* F = side2 ? F1 : F0;
    const int fm = side2 ? bm - 32768 : bm;
    const int* toks = (side2 ? x2 - 32768 : x1) + bm;

    const int wave = tid >> 6;
    const int lane = tid & 63;
    const int wr   = (wave >> 2) * 64;
    const int wc   = (wave & 3) * 32;
    const int lr   = lane & 15;
    const int quad = lane >> 4;
    const int sr   = tid >> 2;
    const int q    = tid & 3;
    const int scf  = q * 8;

    const int tok = toks[sr];
    const float nrm = norms[tok];
    const float* erow = emb + (long long)tok * EDIM;

    const int gn = bn + sr;
    const bool bok = gn < 556;
    const u16* Bhp = Bh + (long long)gn * 320 + scf;
    const u16* Blp = Bl + (long long)gn * 320 + scf;

    f32x4 acc[4][2];
    #pragma unroll
    for (int i = 0; i < 4; i++)
        #pragma unroll
        for (int j = 0; j < 2; j++)
            acc[i][j] = (f32x4)(0.0f);

    float av[8];
    uint4 bh, bl;
    gload_emb8(av, erow, scf);
    bh = bok ? *(const uint4*)(Bhp) : make_uint4(0,0,0,0);
    if (wb) bl = bok ? *(const uint4*)(Blp) : make_uint4(0,0,0,0);

    for (int t = 0; t < 10; ++t) {
        // commit staged regs -> LDS (apply nrm here, not at load)
        {
            float sv[8];
            #pragma unroll
            for (int i = 0; i < 8; i++) sv[i] = av[i] * nrm;
            if (wb) split_store8(sv, smem, smem + 8192, sr, q);
            else    hi_store8(sv, smem, sr, q);
            *(uint4*)swz16(smem + 16384, sr, q) = bh;
            if (wb) *(uint4*)swz16(smem + 24576, sr, q) = bl;
        }
        // prefetch next step (stays in flight across barrier + MFMA)
        if (t < 9) {
            gload_emb8(av, erow, (t + 1) * 32 + scf);
            bh = bok ? *(const uint4*)(Bhp + (t + 1) * 32) : make_uint4(0,0,0,0);
            if (wb) bl = bok ? *(const uint4*)(Blp + (t + 1) * 32) : make_uint4(0,0,0,0);
        }
        __syncthreads();

        bf16x8 fah[4], fbh[2];
        #pragma unroll
        for (int i = 0; i < 4; i++)
            fah[i] = *(const bf16x8*)swz16(smem, wr + i * 16 + lr, quad);
        #pragma unroll
        for (int j = 0; j < 2; j++)
            fbh[j] = *(const bf16x8*)swz16(smem + 16384, wc + j * 16 + lr, quad);
        if (wb) {
            bf16x8 fal[4], fbl[2];
            #pragma unroll
            for (int i = 0; i < 4; i++)
                fal[i] = *(const bf16x8*)swz16(smem + 8192, wr + i * 16 + lr, quad);
            #pragma unroll
            for (int j = 0; j < 2; j++)
                fbl[j] = *(const bf16x8*)swz16(smem + 24576, wc + j * 16 + lr, quad);
            #pragma unroll
            for (int i = 0; i < 4; i++)
                #pragma unroll
                for (int j = 0; j < 2; j++) { MFMA3(i, j) }
        } else {
            #pragma unroll
            for (int i = 0; i < 4; i++)
                #pragma unroll
                for (int j = 0; j < 2; j++) { MFMA1(i, j) }
        }
        __syncthreads();
    }

    if (wb) {
        float* Tb = T + (long long)mt * (PDIM * SEQ);
        store_transposed(Tb, acc, (float*)smem, bn, PDIM, wr, wc, lr, quad, tid, false);
    } else {
        #pragma unroll
        for (int i = 0; i < 4; i++) {
            #pragma unroll
            for (int j = 0; j < 2; j++) {
                const int idx = bn + wc + j * 16 + lr - 256;
                if (idx >= EDIM) continue;
                #pragma unroll
                for (int r = 0; r < 4; r++) {
                    const int gm = fm + wr + i * 16 + quad * 4 + r;
                    F[(long long)gm * EDIM + idx] = fmaxf(acc[i][j][r], 0.f);
                }
            }
        }
    }
}

// ---------------------------------------------------------------------------
// Fused xp GEMM (3-MFMA): acc = e @ wp_a (steps 0..9) + probs @ G (10..13).
// grid (2,1,512), 512 thr, (512,4). Unified 14-step prefetched pipeline.
// ---------------------------------------------------------------------------
__global__ __launch_bounds__(512, 4) void gemm_xp(
    const float* __restrict__ P, float* __restrict__ T,
    const int* __restrict__ x1, const int* __restrict__ x2,
    const float* __restrict__ emb, const float* __restrict__ norms,
    const u16* __restrict__ W1h, const u16* __restrict__ W1l,
    const u16* __restrict__ W2h, const u16* __restrict__ W2l,
    float* __restrict__ XCAT)
{
    __shared__ __align__(16) unsigned char smem[33280];

    const int tid = threadIdx.x;
    const int bz  = blockIdx.z;
    const int bn  = blockIdx.x * 128;

    const int wave = tid >> 6;
    const int lane = tid & 63;
    const int wr   = (wave >> 2) * 64;
    const int wc   = (wave & 3) * 32;
    const int lr   = lane & 15;
    const int quad = lane >> 4;
    const int sr   = tid >> 2;
    const int q    = tid & 3;
    const int scf  = q * 8;

    const int* toks = (bz < BATCH) ? x1 + bz * SEQ : x2 + (bz - BATCH) * SEQ;
    const u16* Wh = (bz < BATCH) ? W1h : W2h;
    const u16* Wl = (bz < BATCH) ? W1l : W2l;
    const int tok = toks[sr];
    const float nrm = norms[tok];
    const float* erow = emb + (long long)tok * EDIM;
    const float* Pb = P + (long long)bz * (SEQ * SEQ);
    float* Tb = T + (long long)bz * (PDIM * SEQ);

    const int gn = bn + sr;
    const bool bok = gn < PDIM;
    const u16* Whp = Wh + (long long)gn * 320 + scf;
    const u16* Wlp = Wl + (long long)gn * 320 + scf;
    const float* Pp = Pb + (long long)sr * 128 + scf;
    const float* Tp = Tb + (long long)gn * 128 + scf;

    f32x4 acc[4][2];
    #pragma unroll
    for (int i = 0; i < 4; i++)
        #pragma unroll
        for (int j = 0; j < 2; j++)
            acc[i][j] = (f32x4)(0.0f);

    float av[8], bv[8];
    uint4 bh, bl;

#define XP_LOAD(sidx) do { \
    if ((sidx) < 10) { \
        gload_emb8(av, erow, (sidx) * 32 + scf); \
        bh = bok ? *(const uint4*)(Whp + (sidx) * 32) : make_uint4(0,0,0,0); \
        bl = bok ? *(const uint4*)(Wlp + (sidx) * 32) : make_uint4(0,0,0,0); \
    } else { \
        gload8(av, Pp + ((sidx) - 10) * 32, true); \
        gload8(bv, Tp + ((sidx) - 10) * 32, bok); \
    } \
} while (0)

    XP_LOAD(0);

    for (int t = 0; t < 14; ++t) {
        if (t < 10) {
            float sv[8];
            #pragma unroll
            for (int i = 0; i < 8; i++) sv[i] = av[i] * nrm;
            split_store8(sv, smem, smem + 8192, sr, q);
            *(uint4*)swz16(smem + 16384, sr, q) = bh;
            *(uint4*)swz16(smem + 24576, sr, q) = bl;
        } else {
            split_store8(av, smem,         smem + 8192,  sr, q);
            split_store8(bv, smem + 16384, smem + 24576, sr, q);
        }
        if (t < 13) XP_LOAD(t + 1);
        __syncthreads();

        bf16x8 fah[4], fal[4], fbh[2], fbl[2];
        #pragma unroll
        for (int i = 0; i < 4; i++) {
            fah[i] = *(const bf16x8*)swz16(smem,        wr + i * 16 + lr, quad);
            fal[i] = *(const bf16x8*)swz16(smem + 8192, wr + i * 16 + lr, quad);
        }
        #pragma unroll
        for (int j = 0; j < 2; j++) {
            fbh[j] = *(const bf16x8*)swz16(smem + 16384, wc + j * 16 + lr, quad);
            fbl[j] = *(const bf16x8*)swz16(smem + 24576, wc + j * 16 + lr, quad);
        }
        #pragma unroll
        for (int i = 0; i < 4; i++)
            #pragma unroll
            for (int j = 0; j < 2; j++) { MFMA3(i, j) }
        __syncthreads();
    }
#undef XP_LOAD

    const long long rowbase = (long long)bz * SEQ;
    #pragma unroll
    for (int i = 0; i < 4; i++) {
        #pragma unroll
        for (int j = 0; j < 2; j++) {
            const int gnn = bn + wc + j * 16 + lr;
            if (gnn >= PDIM) continue;
            #pragma unroll
            for (int r = 0; r < 4; r++) {
                const int gm = wr + i * 16 + quad * 4 + r;
                XCAT[(rowbase + gm) * 400 + gnn] = fmaxf(acc[i][j][r], 0.f);
            }
        }
    }
    store_transposed(Tb, acc, (float*)smem, bn, PDIM, wr, wc, lr, quad, tid, true);
}

// ---------------------------------------------------------------------------
// Flat split-bf16 MFMA GEMM. NM = 3 (split) or 1 (plain bf16 RNE). 512 thr.
// (512,4) + T14 register prefetch.
// ---------------------------------------------------------------------------
template <int NM>
__global__ __launch_bounds__(512, 4) void gemm_flat(
    const float* __restrict__ A,
    const u16* __restrict__ Bh, const u16* __restrict__ Bl,
    const u16* __restrict__ Bh2, const u16* __restrict__ Bl2, int Msplit,
    float* __restrict__ C, float* __restrict__ PO, const int* __restrict__ sizes,
    int M, int N, int Kp, int lda, int ldb, int ldc, int flags)
{
    constexpr int BOFF = (NM == 3) ? 16384 : 8192;
    __shared__ __align__(16) unsigned char smem[(NM == 3) ? 32768 : 16384];

    const int tid = threadIdx.x;
    int bx = blockIdx.x, by = blockIdx.y;
    if ((gridDim.y & 7) == 0) {
        const int gx = gridDim.x;
        const int id = by * gx + bx;
        const int xcd = id & 7;
        const int s = id >> 3;
        by = xcd + 8 * (s / gx);
        bx = s % gx;
    }
    const int bm = by * 128;
    const int bn = bx * 128;

    const int wave = tid >> 6;
    const int lane = tid & 63;
    const int wr   = (wave >> 2) * 64;
    const int wc   = (wave & 3) * 32;
    const int lr   = lane & 15;
    const int quad = lane >> 4;
    const int sr   = tid >> 2;
    const int q    = tid & 3;
    const int scf  = q * 8;

    if (bm >= Msplit) { Bh = Bh2; Bl = Bl2; }

    const float* Ap = A + (long long)(bm + sr) * lda + scf;
    const int gn = bn + sr;
    const bool bok = gn < N;
    const u16* Bhp = Bh + (long long)gn * ldb + scf;
    const u16* Blp = Bl + (long long)gn * ldb + scf;

    f32x4 acc[4][2];
    #pragma unroll
    for (int i = 0; i < 4; i++)
        #pragma unroll
        for (int j = 0; j < 2; j++)
            acc[i][j] = (f32x4)(0.0f);

    const int NT = Kp >> 5;
    float av[8];
    uint4 bh, bl;
    gload8(av, Ap, true);
    bh = bok ? *(const uint4*)(Bhp) : make_uint4(0,0,0,0);
    if constexpr (NM == 3) bl = bok ? *(const uint4*)(Blp) : make_uint4(0,0,0,0);

    for (int t = 0; t < NT; ++t) {
        if constexpr (NM == 3) {
            split_store8(av, smem, smem + 8192, sr, q);
            *(uint4*)swz16(smem + BOFF,        sr, q) = bh;
            *(uint4*)swz16(smem + BOFF + 8192, sr, q) = bl;
        } else {
            hi_store8(av, smem, sr, q);
            *(uint4*)swz16(smem + BOFF, sr, q) = bh;
        }
        if (t < NT - 1) {
            gload8(av, Ap + (t + 1) * 32, true);
            bh = bok ? *(const uint4*)(Bhp + (t + 1) * 32) : make_uint4(0,0,0,0);
            if constexpr (NM == 3)
                bl = bok ? *(const uint4*)(Blp + (t + 1) * 32) : make_uint4(0,0,0,0);
        }
        __syncthreads();

        bf16x8 fah[4], fbh[2];
        #pragma unroll
        for (int i = 0; i < 4; i++)
            fah[i] = *(const bf16x8*)swz16(smem, wr + i * 16 + lr, quad);
        #pragma unroll
        for (int j = 0; j < 2; j++)
            fbh[j] = *(const bf16x8*)swz16(smem + BOFF, wc + j * 16 + lr, quad);
        if constexpr (NM == 3) {
            bf16x8 fal[4], fbl[2];
            #pragma unroll
            for (int i = 0; i < 4; i++)
                fal[i] = *(const bf16x8*)swz16(smem + 8192, wr + i * 16 + lr, quad);
            #pragma unroll
            for (int j = 0; j < 2; j++)
                fbl[j] = *(const bf16x8*)swz16(smem + BOFF + 8192, wc + j * 16 + lr, quad);
            #pragma unroll
            for (int i = 0; i < 4; i++)
                #pragma unroll
                for (int j = 0; j < 2; j++) { MFMA3(i, j) }
        } else {
            #pragma unroll
            for (int i = 0; i < 4; i++)
                #pragma unroll
                for (int j = 0; j < 2; j++) { MFMA1(i, j) }
        }
        __syncthreads();
    }

    const int sz = PO ? sizes[bm >> 7] : 0;
    float ps[2] = {0.f, 0.f};
    #pragma unroll
    for (int j = 0; j < 2; j++) {
        const int gnn = bn + wc + j * 16 + lr;
        const bool gok = gnn < N;
        #pragma unroll
        for (int i = 0; i < 4; i++) {
            #pragma unroll
            for (int r = 0; r < 4; r++) {
                const int row = wr + i * 16 + quad * 4 + r;
                const int gm = bm + row;
                float v = acc[i][j][r];
                if (flags & F_RELU) v = fmaxf(v, 0.f);
                if (gok && C) C[(long long)gm * ldc + gnn] = v;
                if (PO && row < sz) ps[j] += v;
            }
        }
    }
    if (PO) {
        #pragma unroll
        for (int j = 0; j < 2; j++) {
            ps[j] += __shfl_xor(ps[j], 16);
            ps[j] += __shfl_xor(ps[j], 32);
        }
        float* PS = (float*)smem;
        __syncthreads();
        if (wr == 0 && quad == 0) {
            #pragma unroll
            for (int j = 0; j < 2; j++) PS[wc + j * 16 + lr] = ps[j];
        }
        __syncthreads();
        if (wr == 64 && quad == 0) {
            #pragma unroll
            for (int j = 0; j < 2; j++) PS[wc + j * 16 + lr] += ps[j];
        }
        __syncthreads();
        if (tid < 128) {
            const int gnn = bn + tid;
            if (gnn < N) PO[(long long)(bm >> 7) * N + gnn] = PS[tid];
        }
    }
}

// ---------------------------------------------------------------------------
// Batched MFMA GEMM, NT layout, 512 thr.
// MODE 0 (3-MFMA split, (512,4)); MODE 1 (att: dist-bias + IN-REGISTER row
//   softmax -> C; requires same_ab=1; smem 16KB -> multi-block/CU);
// MODE 2 (sim: mask + row softmax -> C + col softmax^T -> PT; LDS S scratch).
// T14 prefetch (kmask deferred to commit). MODE2 scratch stride 132.
// ---------------------------------------------------------------------------
#define SLD 132
template <int MODE>
__global__ __launch_bounds__(512, (MODE == 2) ? 2 : 4) void gemm_bat(
    const float* __restrict__ A, const float* __restrict__ Aalt,
    const float* __restrict__ B, const float* __restrict__ Balt,
    float* __restrict__ C, float* __restrict__ PT,
    int N, int Kvalid, int Kp, int lda, int ldb, int ldc,
    long long sA, long long sB, long long sC, long long sPT,
    int flags, const float* __restrict__ bias_ptr, const int* __restrict__ sizes,
    int same_ab)
{
    constexpr int NM = (MODE == 0) ? 3 : 1;
    constexpr int BOFF = (NM == 3) ? 16384 : 8192;
    constexpr int SMB  = (MODE == 0) ? 32768 : ((MODE == 1) ? 16384 : (128 * SLD * 4));
    __shared__ __align__(16) unsigned char smem[SMB];

    const int bz = blockIdx.z;
    long long zb = bz;
    const float* Ause = A;
    const float* Buse = B;
    if (Aalt && bz >= BATCH) { Ause = Aalt; Buse = Balt; zb = bz - BATCH; }
    Ause += zb * sA;
    Buse += zb * sB;
    C += (long long)bz * sC;
    if (PT) PT += (long long)bz * sPT;

    const int tid  = threadIdx.x;
    const int bn   = blockIdx.x * 128;
    const int wave = tid >> 6;
    const int lane = tid & 63;
    const int wr   = (wave >> 2) * 64;
    const int wc   = (wave & 3) * 32;
    const int lr   = lane & 15;
    const int quad = lane >> 4;
    const int sr   = tid >> 2;
    const int q    = tid & 3;
    const int scf  = q * 8;

    f32x4 acc[4][2];
    #pragma unroll
    for (int i = 0; i < 4; i++)
        #pragma unroll
        for (int j = 0; j < 2; j++)
            acc[i][j] = (f32x4)(0.0f);

    const float* Apt = Ause + (long long)sr * lda + scf;
    const int gn = bn + sr;
    const bool bok = gn < N;
    const float* Bpt = Buse + (long long)gn * ldb + scf;

    const int NT = Kp >> 5;
    float av[8], bv[8];
    gload8(av, Apt, true);
    if (!same_ab) gload8(bv, Bpt, bok);

    for (int t = 0; t < NT; ++t) {
        kmask8(av, t * 32 + scf, Kvalid);
        if constexpr (NM == 3) split_store8(av, smem, smem + 8192, sr, q);
        else                   hi_store8(av, smem, sr, q);
        if (!same_ab) {
            kmask8(bv, t * 32 + scf, Kvalid);
            if constexpr (NM == 3) split_store8(bv, smem + BOFF, smem + BOFF + 8192, sr, q);
            else                   hi_store8(bv, smem + BOFF, sr, q);
        }
        if (t < NT - 1) {
            gload8(av, Apt + (t + 1) * 32, true);
            if (!same_ab) gload8(bv, Bpt + (t + 1) * 32, bok);
        }
        __syncthreads();

        unsigned char* rbB = same_ab ? smem : smem + BOFF;
        bf16x8 fah[4], fbh[2];
        #pragma unroll
        for (int i = 0; i < 4; i++)
            fah[i] = *(const bf16x8*)swz16(smem, wr + i * 16 + lr, quad);
        #pragma unroll
        for (int j = 0; j < 2; j++)
            fbh[j] = *(const bf16x8*)swz16(rbB, wc + j * 16 + lr, quad);
        if constexpr (NM == 3) {
            bf16x8 fal[4], fbl[2];
            #pragma unroll
            for (int i = 0; i < 4; i++)
                fal[i] = *(const bf16x8*)swz16(smem + 8192, wr + i * 16 + lr, quad);
            #pragma unroll
            for (int j = 0; j < 2; j++)
                fbl[j] = *(const bf16x8*)swz16(rbB + 8192, wc + j * 16 + lr, quad);
            #pragma unroll
            for (int i = 0; i < 4; i++)
                #pragma unroll
                for (int j = 0; j < 2; j++) { MFMA3(i, j) }
        } else {
            #pragma unroll
            for (int i = 0; i < 4; i++)
                #pragma unroll
                for (int j = 0; j < 2; j++) { MFMA1(i, j) }
        }
        __syncthreads();
    }

    if (MODE == 1) {
        // In-register row softmax. Lane holds 16 rows x 2 cols; cols of a row
        // live in the 16-lane lr group (shfl_xor 1/2/4/8) + 4 wc-slices across
        // waves (combined via 2KB LDS partials). Statically-indexed locals.
        const float bias = bias_ptr[0];
        float* RED  = (float*)smem;           // [128][4] partial max (2KB)
        float* RED2 = (float*)(smem + 2048);  // [128][4] partial sum (2KB)
        float rmx[4][4];
        #pragma unroll
        for (int i = 0; i < 4; i++) {
            #pragma unroll
            for (int r = 0; r < 4; r++) {
                const int row = wr + i * 16 + quad * 4 + r;
                float m = -1e30f;
                #pragma unroll
                for (int j = 0; j < 2; j++) {
                    const int col = wc + j * 16 + lr;
                    int d = row - col; d = d < 0 ? -d : d;
                    const float v = acc[i][j][r] + ((d >= 10) ? bias : 0.f);
                    acc[i][j][r] = v;
                    m = fmaxf(m, v);
                }
                m = fmaxf(m, __shfl_xor(m, 1));
                m = fmaxf(m, __shfl_xor(m, 2));
                m = fmaxf(m, __shfl_xor(m, 4));
                m = fmaxf(m, __shfl_xor(m, 8));
                rmx[i][r] = m;
            }
        }
        if (lr == 0) {
            #pragma unroll
            for (int i = 0; i < 4; i++)
                #pragma unroll
                for (int r = 0; r < 4; r++)
                    RED[(wr + i * 16 + quad * 4 + r) * 4 + (wave & 3)] = rmx[i][r];
        }
        __syncthreads();
        float rsum[4][4];
        #pragma unroll
        for (int i = 0; i < 4; i++) {
            #pragma unroll
            for (int r = 0; r < 4; r++) {
                const int row = wr + i * 16 + quad * 4 + r;
                const float m = fmaxf(fmaxf(RED[row * 4 + 0], RED[row * 4 + 1]),
                                      fmaxf(RED[row * 4 + 2], RED[row * 4 + 3]));
                float ssum = 0.f;
                #pragma unroll
                for (int j = 0; j < 2; j++) {
                    const float e = __expf(acc[i][j][r] - m);
                    acc[i][j][r] = e;
                    ssum += e;
                }
                ssum += __shfl_xor(ssum, 1);
                ssum += __shfl_xor(ssum, 2);
                ssum += __shfl_xor(ssum, 4);
                ssum += __shfl_xor(ssum, 8);
                rsum[i][r] = ssum;
            }
        }
        if (lr == 0) {
            #pragma unroll
            for (int i = 0; i < 4; i++)
                #pragma unroll
                for (int r = 0; r < 4; r++)
                    RED2[(wr + i * 16 + quad * 4 + r) * 4 + (wave & 3)] = rsum[i][r];
        }
        __syncthreads();
        #pragma unroll
        for (int i = 0; i < 4; i++) {
            #pragma unroll
            for (int r = 0; r < 4; r++) {
                const int row = wr + i * 16 + quad * 4 + r;
                const float stot = (RED2[row * 4 + 0] + RED2[row * 4 + 1])
                                 + (RED2[row * 4 + 2] + RED2[row * 4 + 3]);
                const float inv = 1.f / stot;
                #pragma unroll
                for (int j = 0; j < 2; j++)
                    C[(long long)row * ldc + wc + j * 16 + lr] = acc[i][j][r] * inv;
            }
        }
    } else if (MODE == 2) {
        float* S = (float*)smem;
        const int s1 = sizes[bz];
        const int s2 = sizes[BATCH + bz];
        #pragma unroll
        for (int i = 0; i < 4; i++) {
            #pragma unroll
            for (int j = 0; j < 2; j++) {
                const int col = wc + j * 16 + lr;
                #pragma unroll
                for (int r = 0; r < 4; r++) {
                    const int row = wr + i * 16 + quad * 4 + r;
                    float v = acc[i][j][r];
                    if (row >= s1 || col >= s2) v = 0.f;
                    S[row * SLD + col] = v;
                }
            }
        }
        __syncthreads();
        const int row = tid >> 2;
        const int qd  = (tid & 3) * 32;
        {
            // row softmax (no writeback: column pass needs original S)
            const float* Sr = S + row * SLD + qd;
            float mx = -1e30f;
            #pragma unroll
            for (int c = 0; c < 8; c++) {
                const float4 v = *(const float4*)(Sr + c * 4);
                mx = fmaxf(fmaxf(fmaxf(mx, v.x), fmaxf(v.y, v.z)), v.w);
            }
            mx = fmaxf(mx, __shfl_xor(mx, 1));
            mx = fmaxf(mx, __shfl_xor(mx, 2));
            float sum = 0.f;
            #pragma unroll
            for (int c = 0; c < 8; c++) {
                const float4 v = *(const float4*)(Sr + c * 4);
                sum += (__expf(v.x - mx) + __expf(v.y - mx))
                     + (__expf(v.z - mx) + __expf(v.w - mx));
            }
            sum += __shfl_xor(sum, 1);
            sum += __shfl_xor(sum, 2);
            const float inv = 1.f / sum;
            #pragma unroll
            for (int c = 0; c < 8; c++) {
                const float4 v = *(const float4*)(Sr + c * 4);
                float4 o;
                o.x = __expf(v.x - mx) * inv; o.y = __expf(v.y - mx) * inv;
                o.z = __expf(v.z - mx) * inv; o.w = __expf(v.w - mx) * inv;
                *(float4*)&C[(long long)row * 128 + qd + c * 4] = o;
            }
        }
        {
            // column softmax -> PT (column = tid>>2, rows qd..qd+31)
            const int colx = row;
            float mx = -1e30f;
            for (int r = 0; r < 32; r++)
                mx = fmaxf(mx, S[(qd + r) * SLD + colx]);
            mx = fmaxf(mx, __shfl_xor(mx, 1));
            mx = fmaxf(mx, __shfl_xor(mx, 2));
            float sum = 0.f;
            for (int r = 0; r < 32; r++)
                sum += __expf(S[(qd + r) * SLD + colx] - mx);
            sum += __shfl_xor(sum, 1);
            sum += __shfl_xor(sum, 2);
            const float inv = 1.f / sum;
            #pragma unroll
            for (int r4 = 0; r4 < 8; r4++) {
                float4 o;
                o.x = __expf(S[(qd + r4 * 4 + 0) * SLD + colx] - mx) * inv;
                o.y = __expf(S[(qd + r4 * 4 + 1) * SLD + colx] - mx) * inv;
                o.z = __expf(S[(qd + r4 * 4 + 2) * SLD + colx] - mx) * inv;
                o.w = __expf(S[(qd + r4 * 4 + 3) * SLD + colx] - mx) * inv;
                *(float4*)&PT[(long long)colx * 128 + qd + r4 * 4] = o;
            }
        }
    } else {
        const int s1 = sizes ? sizes[bz] : SEQ;
        const int s2 = sizes ? sizes[BATCH + bz] : SEQ;
        #pragma unroll
        for (int i = 0; i < 4; i++) {
            #pragma unroll
            for (int j = 0; j < 2; j++) {
                const int gnn = bn + wc + j * 16 + lr;
                if (gnn >= N) continue;
                #pragma unroll
                for (int r = 0; r < 4; r++) {
                    const int gm = wr + i * 16 + quad * 4 + r;
                    float v = acc[i][j][r];
                    if (sizes && (gm >= s1 || gnn >= s2)) v = 0.f;
                    if (flags & F_ACCUM) v += C[(long long)gm * ldc + gnn];
                    if (flags & F_RELU)  v = fmaxf(v, 0.f);
                    C[(long long)gm * ldc + gnn] = v;
                    if (PT) PT[(long long)gnn * 128 + gm] = v;
                }
            }
        }
    }
}

// All weight transposes + hi/lo splits in one launch.
struct WEnt { const float* src; u16* H; u16* L; int K, N, Kp, rowStart; };
struct WTab { WEnt e[11]; };
__global__ void convert_all(WTab t)
{
    const int row = blockIdx.y;
    const int k = blockIdx.x * 256 + threadIdx.x;
    #pragma unroll
    for (int s = 0; s < 11; s++) {
        const WEnt w = t.e[s];
        if (row >= w.rowStart && row < w.rowStart + w.N) {
            const int n = row - w.rowStart;
            if (k < w.Kp) {
                const float v = (k < w.K) ? w.src[(long long)k * w.N + n] : 0.f;
                const u16 h = f2bf(v);
                w.H[(long long)n * w.Kp + k] = h;
                w.L[(long long)n * w.Kp + k] = f2bf(v - bf2f(h));
            }
            return;
        }
    }
}

__global__ void norms_kernel(const float* __restrict__ emb, float* __restrict__ norms)
{
    const int r = blockIdx.x;
    const int lane = threadIdx.x;
    const float* row = emb + (long long)r * EDIM;
    float ss = 0.f;
    #pragma unroll
    for (int i = 0; i < 5; i++) {
        const int c = lane + i * 64;
        const float f = (c < EDIM) ? row[c] : 0.f;
        ss += f * f;
    }
    #pragma unroll
    for (int o = 32; o > 0; o >>= 1) ss += __shfl_xor(ss, o);
    if (lane == 0) norms[r] = rsqrtf(fmaxf(ss, 1e-12f));
}

__global__ void sizes_kernel(const int* __restrict__ x1, const int* __restrict__ x2,
                             int* __restrict__ sizes)
{
    const int b = blockIdx.x;
    const int side = blockIdx.y;
    const int* x = (side ? x2 : x1) + b * SEQ;
    const int nz = (x[threadIdx.x] != 0) ? 1 : 0;
    const unsigned long long bal = __ballot(nz);
    __shared__ int part[2];
    if ((threadIdx.x & 63) == 0) part[threadIdx.x >> 6] = __popcll(bal);
    __syncthreads();
    if (threadIdx.x == 0) sizes[side * BATCH + b] = part[0] + part[1];
}

__global__ void agg_kernel(const float* __restrict__ v1s, const float* __restrict__ v2s,
                           const float* __restrict__ w_agg, float* __restrict__ y)
{
    const int b = blockIdx.x;
    const int lane = threadIdx.x;
    float a0 = 0.f, a1 = 0.f, a2 = 0.f;
    for (int k = lane; k < 800; k += 64) {
        const float v = (k < 400) ? v1s[b * 400 + k] : v2s[b * 400 + k - 400];
        a0 = fmaf(v, w_agg[k * 3 + 0], a0);
        a1 = fmaf(v, w_agg[k * 3 + 1], a1);
        a2 = fmaf(v, w_agg[k * 3 + 2], a2);
    }
    #pragma unroll
    for (int o = 32; o > 0; o >>= 1) {
        a0 += __shfl_xor(a0, o);
        a1 += __shfl_xor(a1, o);
        a2 += __shfl_xor(a2, o);
    }
    if (lane == 0) {
        y[b * 3 + 0] = fmaxf(a0, 0.f);
        y[b * 3 + 1] = fmaxf(a1, 0.f);
        y[b * 3 + 2] = fmaxf(a2, 0.f);
    }
}

extern "C" void kernel_launch(void* const* d_in, const int* in_sizes, int n_in,
                              void* d_out, int out_size, void* d_ws, size_t ws_size,
                              hipStream_t stream)
{
    (void)in_sizes; (void)n_in; (void)out_size; (void)ws_size;
    const int*   x1         = (const int*)d_in[0];
    const int*   x2         = (const int*)d_in[1];
    const float* emb        = (const float*)d_in[2];
    const float* w_intra    = (const float*)d_in[3];
    const float* bias_intra = (const float*)d_in[4];
    const float* w_proj1    = (const float*)d_in[5];
    const float* w_proj2    = (const float*)d_in[6];
    const float* w_att      = (const float*)d_in[7];
    const float* w_cmp1     = (const float*)d_in[8];
    const float* w_cmp2     = (const float*)d_in[9];
    const float* w_agg      = (const float*)d_in[10];
    float* y  = (float*)d_out;
    float* ws = (float*)d_ws;

    // ---- workspace (floats); total ~58.64M fl = 234.6 MB ----
    float* X1CAT = ws;                        // [32768,400]: x1p | beta; phase A: F side-2
    float* X2CAT = X1CAT + 13107200;          // [32768,400]: x2p | alpha (contig)
    float* T     = X2CAT + 13107200;          // [512,200,128]: G^T -> x_proj^T
    float* FBUF  = T + 13107200;              // [32768,300] intra f side-1
    float* ATT   = FBUF + 9830400;            // [512,128,128] probs (dead after xp)
    float* POOL  = ATT + 8388608;             // [512,400] pooled v1|v2
    int*   SIZES = (int*)(POOL + 204800);     // [2,256] + pad
    float* NORMS = (float*)(SIZES + 512);     // [32000] + pad
    u16*   W1H   = (u16*)(NORMS + 32768);     // side-1 stack [556][320]: wp_b|z56|intra
    u16*   W1L   = W1H + 177920;
    u16*   W2H   = W1L + 177920;              // side-2 stack [556][320]
    u16*   W2L   = W2H + 177920;
    u16*   WAH   = W2L + 177920;              // w_att^T  [200][224]
    u16*   WAL   = WAH + 44800;
    u16*   WC1H  = WAL + 44800;               // w_cmp1^T [400][416]
    u16*   WC1L  = WC1H + 166400;
    u16*   WC2H  = WC1L + 166400;
    u16*   WC2L  = WC2H + 166400;
    u16*   WPA1H = WC2L + 166400;             // wp_a side1 [200][320]
    u16*   WPA1L = WPA1H + 64000;
    u16*   WPA2H = WPA1L + 64000;
    u16*   WPA2L = WPA2H + 64000;

    // phase-A alias: side-2 intra f lives in X1CAT region (dead until xp)
    float* F1X = X1CAT;                       // [32768,300]
    // phase-B aliases: F12 spans FBUF + head of ATT (probs dead by then)
    float* F12 = FBUF;                        // [65536,200] f1|f2
    float* F2  = FBUF + 6553600;
    // sim outputs alias the f slots they consumed (block-local WAR only):
    float* SIMP = F2;                         // probs slot bz at F2  + bz*25600
    float* SMTP = F12;                        // probs^T slot bz at F12 + bz*25600
    float* T1  = T;
    float* T2  = T + 6553600;

    const long long sbSS = (long long)SEQ * SEQ;     // 16384
    const long long sbF  = (long long)SEQ * EDIM;    // 38400
    const long long sbFP = 25600;                    // f1/f2 slot stride (128*200)
    const long long sbC  = (long long)SEQ * 400;     // 51200
    const long long sbT  = (long long)PDIM * SEQ;    // 25600

    sizes_kernel<<<dim3(BATCH, 2), 128, 0, stream>>>(x1, x2, SIZES);
    norms_kernel<<<32000, 64, 0, stream>>>(emb, NORMS);

    {
        WTab t;
        t.e[0]  = { w_proj1 + 300 * 200, W1H,             W1L,             300, 200, 320, 0    };
        t.e[1]  = { w_intra,             W1H + 200 * 320, W1L + 200 * 320,   0,  56, 320, 200  };
        t.e[2]  = { w_intra,             W1H + 256 * 320, W1L + 256 * 320, 300, 300, 320, 256  };
        t.e[3]  = { w_proj2 + 300 * 200, W2H,             W2L,             300, 200, 320, 556  };
        t.e[4]  = { w_intra,             W2H + 200 * 320, W2L + 200 * 320,   0,  56, 320, 756  };
        t.e[5]  = { w_intra,             W2H + 256 * 320, W2L + 256 * 320, 300, 300, 320, 812  };
        t.e[6]  = { w_att,               WAH,             WAL,             200, 200, 224, 1112 };
        t.e[7]  = { w_cmp1,              WC1H,            WC1L,            400, 400, 416, 1312 };
        t.e[8]  = { w_cmp2,              WC2H,            WC2L,            400, 400, 416, 1712 };
        t.e[9]  = { w_proj1,             WPA1H,           WPA1L,           300, 200, 320, 2112 };
        t.e[10] = { w_proj2,             WPA2H,           WPA2L,           300, 200, 320, 2312 };
        convert_all<<<dim3(2, 2512), 256, 0, stream>>>(t);
    }

    // -------- phase A --------
    // merged proj (both sides): T[0:512] = (e@wp_b)^T; f side1 -> FBUF, side2 -> F1X
    gemm_proj<<<dim3(5, 512), 512, 0, stream>>>(
        x1, x2, emb, NORMS, W1H, W1L, W2H, W2L, T, FBUF, F1X);
    // merged att (512 batches, 1-MFMA): probs = rowsoftmax(f f^T + dbias) -> ATT
    gemm_bat<1><<<dim3(1, 1, 2 * BATCH), 512, 0, stream>>>(
        FBUF, F1X, FBUF, nullptr, ATT, nullptr,
        SEQ, EDIM, 320, EDIM, EDIM, SEQ, sbF, sbF, sbSS, 0,
        0, bias_intra, nullptr, 1);
    // fused xp (3-MFMA): XCAT[:,0:200] = relu(e@wp_a + probs@G); x_proj^T -> T
    gemm_xp<<<dim3(2, 1, 2 * BATCH), 512, 0, stream>>>(
        ATT, T, x1, x2, emb, NORMS, WPA1H, WPA1L, WPA2H, WPA2L, X1CAT);

    // -------- phase B --------
    // f1|f2 = relu(x_proj @ w_att)  [1-MFMA; A cols 200:224 garbage*0]
    gemm_flat<1><<<dim3(2, 512), 512, 0, stream>>>(
        X1CAT, WAH, WAL, WAH, WAL, 1 << 30, F12, nullptr, nullptr,
        2 * BSTOK, PDIM, 224, 400, 224, PDIM, F_RELU);
    // fused sim (1-MFMA): mask(f1 f2^T) -> rowsm over f2 slot + colsm^T over f1 slot
    gemm_bat<2><<<dim3(1, 1, BATCH), 512, 0, stream>>>(
        F12, nullptr, F2, nullptr, SIMP, SMTP,
        SEQ, PDIM, 224, PDIM, PDIM, SEQ, sbFP, sbFP, sbFP, sbFP,
        0, nullptr, SIZES, 0);
    // beta (bz<256) / alpha (bz>=256) -> X1CAT/X2CAT cols 200:400  [3-MFMA]
    gemm_bat<0><<<dim3(2, 1, 2 * BATCH), 512, 0, stream>>>(
        SIMP, SMTP, T2, T1, X1CAT + 200, nullptr,
        PDIM, SEQ, SEQ, SEQ, SEQ, 400, sbFP, sbT, sbC, 0,
        0, nullptr, nullptr, 0);

    // -------- phase C: fused compare + masked pool, aggregate [3-MFMA] --------
    gemm_flat<3><<<dim3(4, 512), 512, 0, stream>>>(
        X1CAT, WC1H, WC1L, WC2H, WC2L, BSTOK,
        nullptr, POOL, SIZES,
        2 * BSTOK, 400, 416, 400, 416, 400, F_RELU);
    agg_kernel<<<BATCH, 64, 0, stream>>>(POOL, POOL + 102400, w_agg, y);
}